// Round 4
// baseline (5004.939 us; speedup 1.0000x reference)
//
#include <hip/hip_runtime.h>
#include <math.h>

#define LRELU(x) ((x) >= 0.f ? (x) : 0.2f*(x))

// ---- static device scratch (285 MB): independent of harness ws_size ----
#define WS_FLOATS 71303168u
__device__ __align__(256) float g_ws[WS_FLOATS];

// ---------------- transpose (B,3,N) -> (B*N,3) ----------------
__global__ __launch_bounds__(256) void k_transpose_in(const float* __restrict__ data,
                                                      float* __restrict__ x0) {
    int i = blockIdx.x*256 + threadIdx.x;      // over B*N = 32768
    int b = i >> 11, n = i & 2047;
    #pragma unroll
    for (int c = 0; c < 3; c++)
        x0[(long)i*3 + c] = data[((long)b*3 + c)*2048 + n];
}

// ---------------- squared norms ----------------
__global__ __launch_bounds__(256) void k_sqnorm(const float* __restrict__ x,
                                                float* __restrict__ sq, int C) {
    int i = blockIdx.x*256 + threadIdx.x;      // over 32768 points
    const float* xr = x + (long)i*C;
    float s = 0.f;
    for (int c = 0; c < C; c++) s = fmaf(xr[c], xr[c], s);
    sq[i] = s;
}

// ---------------- fp32 GEMM: C[i,j] = sum_k A[i,k]*B[j,k] ----------------
// mode 0: store; mode 2: dist epilogue 2*acc - sq[i] - sq[j]
#define KC 8
__global__ __launch_bounds__(256) void k_gemm_nt(
    const float* __restrict__ A, int lda, long sAb,
    const float* __restrict__ B, int ldb, long sBb,
    float* __restrict__ Cm, int ldc, long sCb,
    int K, int Nj, int mode, const float* __restrict__ sq, int sqStride)
{
    __shared__ float As[KC][132];
    __shared__ float Bs[KC][132];
    int z = blockIdx.z;
    const float* Ab = A + (long)z*sAb;
    const float* Bb = B + (long)z*sBb;
    float* Cb = Cm + (long)z*sCb;
    int rowBase = blockIdx.x*128, colBase = blockIdx.y*128;
    int tid = threadIdx.x, tx = tid & 15, ty = tid >> 4;
    float acc[8][8] = {};
    for (int k0 = 0; k0 < K; k0 += KC) {
        #pragma unroll
        for (int l = 0; l < 4; l++) {
            int id = tid + l*256;
            int kk = id & 7, r = id >> 3;   // r in 0..127
            float av = 0.f, bv = 0.f;
            if (k0 + kk < K) {
                av = Ab[(long)(rowBase + r)*lda + k0 + kk];
                if (colBase + r < Nj)
                    bv = Bb[(long)(colBase + r)*ldb + k0 + kk];
            }
            As[kk][r] = av; Bs[kk][r] = bv;
        }
        __syncthreads();
        #pragma unroll
        for (int kk = 0; kk < KC; kk++) {
            float4 a0 = *(const float4*)&As[kk][ty*8];
            float4 a1 = *(const float4*)&As[kk][ty*8 + 4];
            float4 b0 = *(const float4*)&Bs[kk][tx*8];
            float4 b1 = *(const float4*)&Bs[kk][tx*8 + 4];
            float a[8] = {a0.x,a0.y,a0.z,a0.w,a1.x,a1.y,a1.z,a1.w};
            float b[8] = {b0.x,b0.y,b0.z,b0.w,b1.x,b1.y,b1.z,b1.w};
            #pragma unroll
            for (int i = 0; i < 8; i++)
                #pragma unroll
                for (int j = 0; j < 8; j++)
                    acc[i][j] = fmaf(a[i], b[j], acc[i][j]);
        }
        __syncthreads();
    }
    const float* sqz = sq + (long)z*sqStride;  // only dereferenced in mode 2
    #pragma unroll
    for (int i = 0; i < 8; i++) {
        int r = rowBase + ty*8 + i;
        float sqr = (mode == 2) ? sqz[r] : 0.f;
        #pragma unroll
        for (int jj = 0; jj < 8; jj += 4) {
            int c = colBase + tx*8 + jj;
            if (c + 3 < Nj) {
                float4 v;
                v.x = acc[i][jj+0]; v.y = acc[i][jj+1];
                v.z = acc[i][jj+2]; v.w = acc[i][jj+3];
                if (mode == 2) {
                    v.x = 2.f*v.x - sqr - sqz[c+0];
                    v.y = 2.f*v.y - sqr - sqz[c+1];
                    v.z = 2.f*v.z - sqr - sqz[c+2];
                    v.w = 2.f*v.w - sqr - sqz[c+3];
                }
                *(float4*)&Cb[(long)r*ldc + c] = v;
            } else {
                #pragma unroll
                for (int j = jj; j < jj+4; j++) {
                    int c2 = colBase + tx*8 + j;
                    if (c2 >= Nj) continue;
                    float v = acc[i][j];
                    if (mode == 2) v = 2.f*v - sqr - sqz[c2];
                    Cb[(long)r*ldc + c2] = v;
                }
            }
        }
    }
}

// ---------------- fused cat(d1,d2,d3,d4) @ W5^T   (K=512, out 32768x1024) ----------------
__global__ __launch_bounds__(256) void k_gemm_cat(
    const float* __restrict__ d1, const float* __restrict__ d2,
    const float* __restrict__ d3, const float* __restrict__ d4,
    const float* __restrict__ W5, float* __restrict__ Cm)
{
    __shared__ float As[KC][132];
    __shared__ float Bs[KC][132];
    int rowBase = blockIdx.x*128, colBase = blockIdx.y*128;
    int tid = threadIdx.x, tx = tid & 15, ty = tid >> 4;
    float acc[8][8] = {};
    for (int k0 = 0; k0 < 512; k0 += KC) {
        const float* Ab; int lda_, koff;
        if (k0 < 64)       { Ab = d1; lda_ = 64;  koff = k0; }
        else if (k0 < 128) { Ab = d2; lda_ = 64;  koff = k0 - 64; }
        else if (k0 < 256) { Ab = d3; lda_ = 128; koff = k0 - 128; }
        else               { Ab = d4; lda_ = 256; koff = k0 - 256; }
        #pragma unroll
        for (int l = 0; l < 4; l++) {
            int id = tid + l*256;
            int kk = id & 7, r = id >> 3;
            As[kk][r] = Ab[(long)(rowBase + r)*lda_ + koff + kk];
            Bs[kk][r] = W5[(long)(colBase + r)*512 + k0 + kk];
        }
        __syncthreads();
        #pragma unroll
        for (int kk = 0; kk < KC; kk++) {
            float4 a0 = *(const float4*)&As[kk][ty*8];
            float4 a1 = *(const float4*)&As[kk][ty*8 + 4];
            float4 b0 = *(const float4*)&Bs[kk][tx*8];
            float4 b1 = *(const float4*)&Bs[kk][tx*8 + 4];
            float a[8] = {a0.x,a0.y,a0.z,a0.w,a1.x,a1.y,a1.z,a1.w};
            float b[8] = {b0.x,b0.y,b0.z,b0.w,b1.x,b1.y,b1.z,b1.w};
            #pragma unroll
            for (int i = 0; i < 8; i++)
                #pragma unroll
                for (int j = 0; j < 8; j++)
                    acc[i][j] = fmaf(a[i], b[j], acc[i][j]);
        }
        __syncthreads();
    }
    #pragma unroll
    for (int i = 0; i < 8; i++) {
        long r = rowBase + ty*8 + i;
        #pragma unroll
        for (int jj = 0; jj < 8; jj += 4) {
            int c = colBase + tx*8 + jj;
            float4 v;
            v.x = acc[i][jj+0]; v.y = acc[i][jj+1];
            v.z = acc[i][jj+2]; v.w = acc[i][jj+3];
            *(float4*)&Cm[r*1024 + c] = v;
        }
    }
}

// ---------------- top-20 per row (value desc, index asc ties) ----------------
__global__ __launch_bounds__(256) void k_topk20(const float* __restrict__ dist,
                                                int* __restrict__ idxOut, int rowOffset)
{
    __shared__ float lds[4][2048];
    int wave = threadIdx.x >> 6, lane = threadIdx.x & 63;
    int row = blockIdx.x*4 + wave;
    const float* dr = dist + (long)row*2048;
    float* L = lds[wave];
    for (int i = 0; i < 32; i++) L[i*64 + lane] = dr[i*64 + lane];
    __syncthreads();
    int* out = idxOut + (long)(rowOffset + row)*20;
    for (int it = 0; it < 20; it++) {
        float bv = -INFINITY; int bi = 0x7fffffff;
        for (int i = 0; i < 32; i++) {
            float v = L[i*64 + lane];
            if (v > bv) { bv = v; bi = i*64 + lane; }
        }
        #pragma unroll
        for (int s = 32; s > 0; s >>= 1) {
            float ov = __shfl_xor(bv, s);
            int   oi = __shfl_xor(bi, s);
            if (ov > bv || (ov == bv && oi < bi)) { bv = ov; bi = oi; }
        }
        if (lane == 0) out[it] = bi;
        if (lane == (bi & 63)) L[bi] = -INFINITY;
    }
}

// ---------------- Wd = W[:,C:] - W[:,:C] ----------------
__global__ __launch_bounds__(256) void k_wdiff(const float* __restrict__ W,
                                               float* __restrict__ Wd, int O, int C) {
    int i = blockIdx.x*256 + threadIdx.x;
    if (i >= O*C) return;
    int o = i / C, c = i % C;
    Wd[o*C + c] = W[(long)o*2*C + C + c] - W[(long)o*2*C + c];
}

// ---------------- fused gather: hmax/hmin per (pt,c) + block stats partials ----------------
// grid 2048 blocks x 256 thr; 16 points/block; thread handles 4 channels (c4)
__global__ __launch_bounds__(256) void k_edge_gather(
    const float* __restrict__ p, const float* __restrict__ q,
    const int* __restrict__ idx,
    float* __restrict__ hmax, float* __restrict__ hmin,
    float* __restrict__ partial, int O, int lg2TPP)
{
    __shared__ float ldsS[1024];
    __shared__ float ldsS2[1024];
    int tid = threadIdx.x;
    int TPP = O >> 2;                    // threads per point
    int c4 = (tid & (TPP - 1)) << 2;
    int sub = tid >> lg2TPP;
    int nsub = 256 >> lg2TPP;            // points in flight
    int wg = blockIdx.x;
    int logical = (wg & 7)*256 + (wg >> 3);   // XCD swizzle: 2 batches per XCD
    int base = logical*16;
    float4 s = {0,0,0,0}, s2 = {0,0,0,0};
    int iters = 16 / nsub;
    for (int it = 0; it < iters; ++it) {
        int pt = base + sub + it*nsub;
        int bb = (pt >> 11) << 11;
        const int* ir = idx + (long)pt*20;
        float4 qv = *(const float4*)&q[(long)pt*O + c4];
        float4 mx = {-INFINITY,-INFINITY,-INFINITY,-INFINITY};
        float4 mn = { INFINITY, INFINITY, INFINITY, INFINITY};
        for (int k = 0; k < 20; ++k) {
            int m = ir[k];
            float4 pv = *(const float4*)&p[(long)(bb + m)*O + c4];
            float4 h;
            h.x = pv.x + qv.x; h.y = pv.y + qv.y;
            h.z = pv.z + qv.z; h.w = pv.w + qv.w;
            mx.x = fmaxf(mx.x, h.x); mx.y = fmaxf(mx.y, h.y);
            mx.z = fmaxf(mx.z, h.z); mx.w = fmaxf(mx.w, h.w);
            mn.x = fminf(mn.x, h.x); mn.y = fminf(mn.y, h.y);
            mn.z = fminf(mn.z, h.z); mn.w = fminf(mn.w, h.w);
            s.x += h.x; s.y += h.y; s.z += h.z; s.w += h.w;
            s2.x = fmaf(h.x, h.x, s2.x); s2.y = fmaf(h.y, h.y, s2.y);
            s2.z = fmaf(h.z, h.z, s2.z); s2.w = fmaf(h.w, h.w, s2.w);
        }
        *(float4*)&hmax[(long)pt*O + c4] = mx;
        *(float4*)&hmin[(long)pt*O + c4] = mn;
    }
    *(float4*)&ldsS [sub*O + c4] = s;
    *(float4*)&ldsS2[sub*O + c4] = s2;
    __syncthreads();
    if (tid < O) {
        float a = 0.f, b = 0.f;
        for (int u = 0; u < nsub; ++u) { a += ldsS[u*O + tid]; b += ldsS2[u*O + tid]; }
        partial[(long)wg*2*O + tid] = a;
        partial[(long)wg*2*O + O + tid] = b;
    }
}

// ---------------- column sum of partials: sums[c] = sum_r partial[r][c] ----------------
__global__ __launch_bounds__(256) void k_stats_sum(const float* __restrict__ partial,
                                                   float* __restrict__ sums, int W, int R) {
    int c = blockIdx.x*256 + threadIdx.x;
    if (c >= W) return;
    float s = 0.f;
    for (int r = 0; r < R; ++r) s += partial[(long)r*W + c];
    sums[c] = s;
}

// ---------------- scale/shift from sums ----------------
__global__ __launch_bounds__(256) void k_bn_finalize(
    const float* __restrict__ sums, const float* __restrict__ g,
    const float* __restrict__ beta, float* __restrict__ ss, int O, float invCnt)
{
    int o = blockIdx.x*256 + threadIdx.x;
    if (o >= O) return;
    float mean = sums[o]*invCnt;
    float var  = sums[O + o]*invCnt - mean*mean;
    float sc = g[o] * rsqrtf(var + 1e-5f);
    ss[o] = sc;
    ss[O + o] = beta[o] - mean*sc;
}

// ---------------- apply BN + lrelu to hmax/hmin ----------------
__global__ __launch_bounds__(256) void k_edge_apply(
    const float* __restrict__ hmax, const float* __restrict__ hmin,
    const float* __restrict__ ss, float* __restrict__ out, int O)
{
    long i4 = (long)blockIdx.x*256 + threadIdx.x;   // float4 index
    int c4 = (int)(i4 & ((O >> 2) - 1)) << 2;
    float4 mx = *(const float4*)&hmax[i4*4];
    float4 mn = *(const float4*)&hmin[i4*4];
    float4 y;
    {
        float sc = ss[c4+0], sh = ss[O+c4+0];
        float v = fmaf(sc >= 0.f ? mx.x : mn.x, sc, sh); y.x = LRELU(v);
    }
    {
        float sc = ss[c4+1], sh = ss[O+c4+1];
        float v = fmaf(sc >= 0.f ? mx.y : mn.y, sc, sh); y.y = LRELU(v);
    }
    {
        float sc = ss[c4+2], sh = ss[O+c4+2];
        float v = fmaf(sc >= 0.f ? mx.z : mn.z, sc, sh); y.z = LRELU(v);
    }
    {
        float sc = ss[c4+3], sh = ss[O+c4+3];
        float v = fmaf(sc >= 0.f ? mx.w : mn.w, sc, sh); y.w = LRELU(v);
    }
    *(float4*)&out[i4*4] = y;
}

// ---------------- h5 stats partials (deterministic) ----------------
__global__ __launch_bounds__(256) void k_h5_stats_p(const float* __restrict__ h5,
                                                    float* __restrict__ partial) {
    int tid = threadIdx.x, bid = blockIdx.x;   // 2048 blocks, 16 points each
    int base = bid*16;
    float s[4] = {0,0,0,0}, s2[4] = {0,0,0,0};
    for (int i = 0; i < 16; ++i) {
        long row = (long)(base + i)*1024;
        #pragma unroll
        for (int cc = 0; cc < 4; ++cc) {
            float v = h5[row + cc*256 + tid];
            s[cc] += v; s2[cc] = fmaf(v, v, s2[cc]);
        }
    }
    #pragma unroll
    for (int cc = 0; cc < 4; ++cc) {
        partial[(long)bid*2048 + cc*256 + tid] = s[cc];
        partial[(long)bid*2048 + 1024 + cc*256 + tid] = s2[cc];
    }
}

// ---------------- f-reduction stage A: per 128-row chunk max/sum of y ----------------
__global__ __launch_bounds__(256) void k_reduce_fp(const float* __restrict__ h5,
                                                   const float* __restrict__ ss,
                                                   float* __restrict__ fpart) {
    int b = blockIdx.x, ch = blockIdx.y;
    int c = blockIdx.z*256 + threadIdx.x;
    float sc = ss[c], sh = ss[1024 + c];
    float mx = -INFINITY, sm = 0.f;
    int n0 = ch*128;
    for (int n = n0; n < n0 + 128; ++n) {
        float v = h5[((long)(b*2048 + n))*1024 + c];
        float y = fmaf(v, sc, sh); y = LRELU(y);
        mx = fmaxf(mx, y); sm += y;
    }
    fpart[((long)(b*16 + ch))*2048 + c] = mx;
    fpart[((long)(b*16 + ch))*2048 + 1024 + c] = sm;
}

// ---------------- f-reduction stage B ----------------
__global__ __launch_bounds__(256) void k_reduce_ff(const float* __restrict__ fpart,
                                                   float* __restrict__ f) {
    int b = blockIdx.x;
    int c = blockIdx.y*256 + threadIdx.x;
    float mx = -INFINITY, sm = 0.f;
    for (int ch = 0; ch < 16; ++ch) {
        mx = fmaxf(mx, fpart[((long)(b*16 + ch))*2048 + c]);
        sm += fpart[((long)(b*16 + ch))*2048 + 1024 + c];
    }
    f[(long)b*2048 + c] = mx;
    f[(long)b*2048 + 1024 + c] = sm * (1.f/2048.f);
}

// ---------------- small FC matmul: Y[b,j] = X[b,:].W[j,:] + bias ----------------
__global__ __launch_bounds__(256) void k_fc_mm(const float* __restrict__ X,
                                               const float* __restrict__ W,
                                               const float* __restrict__ bias,
                                               float* __restrict__ Y,
                                               int Kdim, int Ncol) {
    int t = blockIdx.x*256 + threadIdx.x;
    if (t >= 16*Ncol) return;
    int b = t / Ncol, j = t % Ncol;
    const float* xr = X + (long)b*Kdim;
    const float* wr = W + (long)j*Kdim;
    float s = 0.f;
    for (int k = 0; k < Kdim; k++) s = fmaf(xr[k], wr[k], s);
    Y[t] = s + (bias ? bias[j] : 0.f);
}

// ---------------- BN over batch axis (16) + lrelu ----------------
__global__ __launch_bounds__(256) void k_bn_rows(const float* __restrict__ X,
                                                 const float* __restrict__ g,
                                                 const float* __restrict__ be,
                                                 float* __restrict__ Y, int Ncol) {
    int j = blockIdx.x*256 + threadIdx.x;
    if (j >= Ncol) return;
    float s = 0.f, s2 = 0.f;
    for (int b = 0; b < 16; b++) { float v = X[b*Ncol + j]; s += v; s2 = fmaf(v, v, s2); }
    float mean = s*(1.f/16.f);
    float var  = s2*(1.f/16.f) - mean*mean;
    float sc = g[j]*rsqrtf(var + 1e-5f);
    float sh = be[j] - mean*sc;
    for (int b = 0; b < 16; b++) {
        float v = fmaf(X[b*Ncol + j], sc, sh);
        Y[b*Ncol + j] = LRELU(v);
    }
}

extern "C" void kernel_launch(void* const* d_in, const int* in_sizes, int n_in,
                              void* d_out, int out_size, void* d_ws, size_t ws_size,
                              hipStream_t stream) {
    const float* data = (const float*)d_in[0];
    const float* W1 = (const float*)d_in[1];  const float* g1 = (const float*)d_in[2];  const float* b1 = (const float*)d_in[3];
    const float* W2 = (const float*)d_in[4];  const float* g2 = (const float*)d_in[5];  const float* b2 = (const float*)d_in[6];
    const float* W3 = (const float*)d_in[7];  const float* g3 = (const float*)d_in[8];  const float* b3 = (const float*)d_in[9];
    const float* W4 = (const float*)d_in[10]; const float* g4 = (const float*)d_in[11]; const float* b4 = (const float*)d_in[12];
    const float* W5 = (const float*)d_in[13]; const float* g5 = (const float*)d_in[14]; const float* b5 = (const float*)d_in[15];
    const float* fc1W = (const float*)d_in[16]; const float* bn1g = (const float*)d_in[17]; const float* bn1b = (const float*)d_in[18];
    const float* fc2W = (const float*)d_in[19]; const float* fc2b = (const float*)d_in[20];
    const float* bn2g = (const float*)d_in[21]; const float* bn2b = (const float*)d_in[22];
    const float* fc3W = (const float*)d_in[23]; const float* fc3b = (const float*)d_in[24];

    void* wsym = nullptr;
    hipGetSymbolAddress(&wsym, HIP_SYMBOL(g_ws));
    char* w = (char*)wsym;
    size_t off = 0;
    auto alloc = [&](size_t bytes) { void* r = w + off; off += (bytes + 255) & ~size_t(255); return r; };
    float* S   = (float*)alloc(134217728);      // dist (8 batches) / h5 / hmax+hmin+partial
    float* x0  = (float*)alloc(393216);
    float* d1  = (float*)alloc(8388608);
    float* d2  = (float*)alloc(8388608);
    float* d3  = (float*)alloc(16777216);
    float* d4  = (float*)alloc(33554432);
    float* p   = (float*)alloc(33554432);
    float* q   = (float*)alloc(33554432);
    int*   idxb= (int*)  alloc(2621440);
    float* sqb = (float*)alloc(131072);
    float* Wd  = (float*)alloc(131072);
    float* sums= (float*)alloc(8192);
    float* ssb = (float*)alloc(8192);
    float* f   = (float*)alloc(131072);
    float* t1  = (float*)alloc(32768);
    float* a1  = (float*)alloc(32768);
    float* t2  = (float*)alloc(16384);
    float* a2  = (float*)alloc(16384);
    (void)ws_size; (void)n_in; (void)in_sizes; (void)out_size; (void)d_ws;

    // aliases inside S (live ranges don't overlap):
    float* hmaxb = S;                 // 32768*O <= 8.39M floats
    float* hminb = S + 8388608;
    float* partb = S + 16777216;      // <= 1.05M floats
    float* h5par = d4;                // h5 stats partials (16 MB), d4 dead after cat-GEMM
    float* fpart = d1;                // f-reduce partials (2 MB), d1 dead after cat-GEMM

    k_transpose_in<<<128, 256, 0, stream>>>(data, x0);

    auto layer = [&](const float* x, int C, int O, int lg2TPP, const float* W,
                     const float* g, const float* beta, float* out) {
        k_sqnorm<<<128, 256, 0, stream>>>(x, sqb, C);
        for (int ch = 0; ch < 2; ch++) {
            const float* xc = x + (long)ch*16384*C;
            k_gemm_nt<<<dim3(16,16,8), 256, 0, stream>>>(
                xc, C, (long)2048*C, xc, C, (long)2048*C,
                S, 2048, (long)2048*2048, C, 2048, 2, sqb + ch*16384, 2048);
            k_topk20<<<4096, 256, 0, stream>>>(S, idxb, ch*16384);
        }
        k_wdiff<<<(O*C + 255)/256, 256, 0, stream>>>(W, Wd, O, C);
        k_gemm_nt<<<dim3(256, (O+127)/128, 1), 256, 0, stream>>>(
            x, C, 0, W, 2*C, 0, p, O, 0, C, O, 0, nullptr, 0);
        k_gemm_nt<<<dim3(256, (O+127)/128, 1), 256, 0, stream>>>(
            x, C, 0, Wd, C, 0, q, O, 0, C, O, 0, nullptr, 0);
        k_edge_gather<<<2048, 256, 0, stream>>>(p, q, idxb, hmaxb, hminb, partb, O, lg2TPP);
        k_stats_sum<<<(2*O + 255)/256, 256, 0, stream>>>(partb, sums, 2*O, 2048);
        k_bn_finalize<<<(O+255)/256, 256, 0, stream>>>(sums, g, beta, ssb, O, 1.f/655360.f);
        k_edge_apply<<<32*O, 256, 0, stream>>>(hmaxb, hminb, ssb, out, O);
    };

    layer(x0, 3,   64,  4, W1, g1, b1, d1);
    layer(d1, 64,  64,  4, W2, g2, b2, d2);
    layer(d2, 64,  128, 5, W3, g3, b3, d3);
    layer(d3, 128, 256, 6, W4, g4, b4, d4);

    // fused h5 = cat(d1,d2,d3,d4) @ W5^T  -> S
    k_gemm_cat<<<dim3(256,8,1), 256, 0, stream>>>(d1, d2, d3, d4, W5, S);

    // h5 BN stats (deterministic partials) + fused BN+lrelu+max/mean reduce
    k_h5_stats_p<<<2048, 256, 0, stream>>>(S, h5par);
    k_stats_sum<<<8, 256, 0, stream>>>(h5par, sums, 2048, 2048);
    k_bn_finalize<<<4, 256, 0, stream>>>(sums, g5, b5, ssb, 1024, 1.f/32768.f);
    k_reduce_fp<<<dim3(16,16,4), 256, 0, stream>>>(S, ssb, fpart);
    k_reduce_ff<<<dim3(16,4), 256, 0, stream>>>(fpart, f);

    k_fc_mm<<<32, 256, 0, stream>>>(f,  fc1W, nullptr, t1, 2048, 512);
    k_bn_rows<<<2, 256, 0, stream>>>(t1, bn1g, bn1b, a1, 512);
    k_fc_mm<<<16, 256, 0, stream>>>(a1, fc2W, fc2b, t2, 512, 256);
    k_bn_rows<<<1, 256, 0, stream>>>(t2, bn2g, bn2b, a2, 256);
    k_fc_mm<<<3, 256, 0, stream>>>(a2, fc3W, fc3b, (float*)d_out, 256, 40);
}

// Round 5
// 2799.521 us; speedup vs baseline: 1.7878x; 1.7878x over previous
//
#include <hip/hip_runtime.h>
#include <math.h>

#define LRELU(x) ((x) >= 0.f ? (x) : 0.2f*(x))

// ---- static device scratch (285 MB): independent of harness ws_size ----
#define WS_FLOATS 71303168u
__device__ __align__(256) float g_ws[WS_FLOATS];

// ---------------- transpose (B,3,N) -> (B*N,3) ----------------
__global__ __launch_bounds__(256) void k_transpose_in(const float* __restrict__ data,
                                                      float* __restrict__ x0) {
    int i = blockIdx.x*256 + threadIdx.x;      // over B*N = 32768
    int b = i >> 11, n = i & 2047;
    #pragma unroll
    for (int c = 0; c < 3; c++)
        x0[(long)i*3 + c] = data[((long)b*3 + c)*2048 + n];
}

// ---------------- squared norms ----------------
__global__ __launch_bounds__(256) void k_sqnorm(const float* __restrict__ x,
                                                float* __restrict__ sq, int C) {
    int i = blockIdx.x*256 + threadIdx.x;      // over 32768 points
    const float* xr = x + (long)i*C;
    float s = 0.f;
    for (int c = 0; c < C; c++) s = fmaf(xr[c], xr[c], s);
    sq[i] = s;
}

// ---------------- fp32 GEMM: C[i,j] = sum_k A[i,k]*B[j,k] ----------------
// mode 0: store; mode 2: dist epilogue 2*acc - sq[i] - sq[j]
#define KC 8
__global__ __launch_bounds__(256) void k_gemm_nt(
    const float* __restrict__ A, int lda, long sAb,
    const float* __restrict__ B, int ldb, long sBb,
    float* __restrict__ Cm, int ldc, long sCb,
    int K, int Nj, int mode, const float* __restrict__ sq, int sqStride)
{
    __shared__ float As[KC][132];
    __shared__ float Bs[KC][132];
    int z = blockIdx.z;
    const float* Ab = A + (long)z*sAb;
    const float* Bb = B + (long)z*sBb;
    float* Cb = Cm + (long)z*sCb;
    int rowBase = blockIdx.x*128, colBase = blockIdx.y*128;
    int tid = threadIdx.x, tx = tid & 15, ty = tid >> 4;
    float acc[8][8] = {};
    for (int k0 = 0; k0 < K; k0 += KC) {
        #pragma unroll
        for (int l = 0; l < 4; l++) {
            int id = tid + l*256;
            int kk = id & 7, r = id >> 3;   // r in 0..127
            float av = 0.f, bv = 0.f;
            if (k0 + kk < K) {
                av = Ab[(long)(rowBase + r)*lda + k0 + kk];
                if (colBase + r < Nj)
                    bv = Bb[(long)(colBase + r)*ldb + k0 + kk];
            }
            As[kk][r] = av; Bs[kk][r] = bv;
        }
        __syncthreads();
        #pragma unroll
        for (int kk = 0; kk < KC; kk++) {
            float4 a0 = *(const float4*)&As[kk][ty*8];
            float4 a1 = *(const float4*)&As[kk][ty*8 + 4];
            float4 b0 = *(const float4*)&Bs[kk][tx*8];
            float4 b1 = *(const float4*)&Bs[kk][tx*8 + 4];
            float a[8] = {a0.x,a0.y,a0.z,a0.w,a1.x,a1.y,a1.z,a1.w};
            float b[8] = {b0.x,b0.y,b0.z,b0.w,b1.x,b1.y,b1.z,b1.w};
            #pragma unroll
            for (int i = 0; i < 8; i++)
                #pragma unroll
                for (int j = 0; j < 8; j++)
                    acc[i][j] = fmaf(a[i], b[j], acc[i][j]);
        }
        __syncthreads();
    }
    const float* sqz = sq + (long)z*sqStride;  // only dereferenced in mode 2
    #pragma unroll
    for (int i = 0; i < 8; i++) {
        int r = rowBase + ty*8 + i;
        float sqr = (mode == 2) ? sqz[r] : 0.f;
        #pragma unroll
        for (int jj = 0; jj < 8; jj += 4) {
            int c = colBase + tx*8 + jj;
            if (c + 3 < Nj) {
                float4 v;
                v.x = acc[i][jj+0]; v.y = acc[i][jj+1];
                v.z = acc[i][jj+2]; v.w = acc[i][jj+3];
                if (mode == 2) {
                    v.x = 2.f*v.x - sqr - sqz[c+0];
                    v.y = 2.f*v.y - sqr - sqz[c+1];
                    v.z = 2.f*v.z - sqr - sqz[c+2];
                    v.w = 2.f*v.w - sqr - sqz[c+3];
                }
                *(float4*)&Cb[(long)r*ldc + c] = v;
            } else {
                #pragma unroll
                for (int j = jj; j < jj+4; j++) {
                    int c2 = colBase + tx*8 + j;
                    if (c2 >= Nj) continue;
                    float v = acc[i][j];
                    if (mode == 2) v = 2.f*v - sqr - sqz[c2];
                    Cb[(long)r*ldc + c2] = v;
                }
            }
        }
    }
}

// ---------------- fused cat(d1,d2,d3,d4) @ W5^T   (K=512, out 32768x1024) ----------------
__global__ __launch_bounds__(256) void k_gemm_cat(
    const float* __restrict__ d1, const float* __restrict__ d2,
    const float* __restrict__ d3, const float* __restrict__ d4,
    const float* __restrict__ W5, float* __restrict__ Cm)
{
    __shared__ float As[KC][132];
    __shared__ float Bs[KC][132];
    int rowBase = blockIdx.x*128, colBase = blockIdx.y*128;
    int tid = threadIdx.x, tx = tid & 15, ty = tid >> 4;
    float acc[8][8] = {};
    for (int k0 = 0; k0 < 512; k0 += KC) {
        const float* Ab; int lda_, koff;
        if (k0 < 64)       { Ab = d1; lda_ = 64;  koff = k0; }
        else if (k0 < 128) { Ab = d2; lda_ = 64;  koff = k0 - 64; }
        else if (k0 < 256) { Ab = d3; lda_ = 128; koff = k0 - 128; }
        else               { Ab = d4; lda_ = 256; koff = k0 - 256; }
        #pragma unroll
        for (int l = 0; l < 4; l++) {
            int id = tid + l*256;
            int kk = id & 7, r = id >> 3;
            As[kk][r] = Ab[(long)(rowBase + r)*lda_ + koff + kk];
            Bs[kk][r] = W5[(long)(colBase + r)*512 + k0 + kk];
        }
        __syncthreads();
        #pragma unroll
        for (int kk = 0; kk < KC; kk++) {
            float4 a0 = *(const float4*)&As[kk][ty*8];
            float4 a1 = *(const float4*)&As[kk][ty*8 + 4];
            float4 b0 = *(const float4*)&Bs[kk][tx*8];
            float4 b1 = *(const float4*)&Bs[kk][tx*8 + 4];
            float a[8] = {a0.x,a0.y,a0.z,a0.w,a1.x,a1.y,a1.z,a1.w};
            float b[8] = {b0.x,b0.y,b0.z,b0.w,b1.x,b1.y,b1.z,b1.w};
            #pragma unroll
            for (int i = 0; i < 8; i++)
                #pragma unroll
                for (int j = 0; j < 8; j++)
                    acc[i][j] = fmaf(a[i], b[j], acc[i][j]);
        }
        __syncthreads();
    }
    #pragma unroll
    for (int i = 0; i < 8; i++) {
        long r = rowBase + ty*8 + i;
        #pragma unroll
        for (int jj = 0; jj < 8; jj += 4) {
            int c = colBase + tx*8 + jj;
            float4 v;
            v.x = acc[i][jj+0]; v.y = acc[i][jj+1];
            v.z = acc[i][jj+2]; v.w = acc[i][jj+3];
            *(float4*)&Cm[r*1024 + c] = v;
        }
    }
}

// ---------------- top-20 per row (value desc, index asc ties) ----------------
__global__ __launch_bounds__(256) void k_topk20(const float* __restrict__ dist,
                                                int* __restrict__ idxOut, int rowOffset)
{
    __shared__ float lds[4][2048];
    int wave = threadIdx.x >> 6, lane = threadIdx.x & 63;
    int row = blockIdx.x*4 + wave;
    const float* dr = dist + (long)row*2048;
    float* L = lds[wave];
    for (int i = 0; i < 32; i++) L[i*64 + lane] = dr[i*64 + lane];
    __syncthreads();
    int* out = idxOut + (long)(rowOffset + row)*20;
    for (int it = 0; it < 20; it++) {
        float bv = -INFINITY; int bi = 0x7fffffff;
        for (int i = 0; i < 32; i++) {
            float v = L[i*64 + lane];
            if (v > bv) { bv = v; bi = i*64 + lane; }
        }
        #pragma unroll
        for (int s = 32; s > 0; s >>= 1) {
            float ov = __shfl_xor(bv, s);
            int   oi = __shfl_xor(bi, s);
            if (ov > bv || (ov == bv && oi < bi)) { bv = ov; bi = oi; }
        }
        if (lane == 0) out[it] = bi;
        if (lane == (bi & 63)) L[bi] = -INFINITY;
    }
}

// ---------------- Wd = W[:,C:] - W[:,:C] ----------------
__global__ __launch_bounds__(256) void k_wdiff(const float* __restrict__ W,
                                               float* __restrict__ Wd, int O, int C) {
    int i = blockIdx.x*256 + threadIdx.x;
    if (i >= O*C) return;
    int o = i / C, c = i % C;
    Wd[o*C + c] = W[(long)o*2*C + C + c] - W[(long)o*2*C + c];
}

// ---------------- fused gather: hmax/hmin per (pt,c) + block stats partials ----------------
// grid 2048 blocks x 256 thr; 16 points/block; thread handles 4 channels (c4)
__global__ __launch_bounds__(256) void k_edge_gather(
    const float* __restrict__ p, const float* __restrict__ q,
    const int* __restrict__ idx,
    float* __restrict__ hmax, float* __restrict__ hmin,
    float* __restrict__ partial, int O, int lg2TPP)
{
    __shared__ float ldsS[1024];
    __shared__ float ldsS2[1024];
    int tid = threadIdx.x;
    int TPP = O >> 2;                    // threads per point
    int c4 = (tid & (TPP - 1)) << 2;
    int sub = tid >> lg2TPP;
    int nsub = 256 >> lg2TPP;            // points in flight
    int wg = blockIdx.x;
    int logical = (wg & 7)*256 + (wg >> 3);   // XCD swizzle: 2 batches per XCD
    int base = logical*16;
    float4 s = {0,0,0,0}, s2 = {0,0,0,0};
    int iters = 16 / nsub;
    for (int it = 0; it < iters; ++it) {
        int pt = base + sub + it*nsub;
        int bb = (pt >> 11) << 11;
        const int* ir = idx + (long)pt*20;
        float4 qv = *(const float4*)&q[(long)pt*O + c4];
        float4 mx = {-INFINITY,-INFINITY,-INFINITY,-INFINITY};
        float4 mn = { INFINITY, INFINITY, INFINITY, INFINITY};
        for (int k = 0; k < 20; ++k) {
            int m = ir[k];
            float4 pv = *(const float4*)&p[(long)(bb + m)*O + c4];
            float4 h;
            h.x = pv.x + qv.x; h.y = pv.y + qv.y;
            h.z = pv.z + qv.z; h.w = pv.w + qv.w;
            mx.x = fmaxf(mx.x, h.x); mx.y = fmaxf(mx.y, h.y);
            mx.z = fmaxf(mx.z, h.z); mx.w = fmaxf(mx.w, h.w);
            mn.x = fminf(mn.x, h.x); mn.y = fminf(mn.y, h.y);
            mn.z = fminf(mn.z, h.z); mn.w = fminf(mn.w, h.w);
            s.x += h.x; s.y += h.y; s.z += h.z; s.w += h.w;
            s2.x = fmaf(h.x, h.x, s2.x); s2.y = fmaf(h.y, h.y, s2.y);
            s2.z = fmaf(h.z, h.z, s2.z); s2.w = fmaf(h.w, h.w, s2.w);
        }
        *(float4*)&hmax[(long)pt*O + c4] = mx;
        *(float4*)&hmin[(long)pt*O + c4] = mn;
    }
    *(float4*)&ldsS [sub*O + c4] = s;
    *(float4*)&ldsS2[sub*O + c4] = s2;
    __syncthreads();
    if (tid < O) {
        float a = 0.f, b = 0.f;
        for (int u = 0; u < nsub; ++u) { a += ldsS[u*O + tid]; b += ldsS2[u*O + tid]; }
        partial[(long)wg*2*O + tid] = a;
        partial[(long)wg*2*O + O + tid] = b;
    }
}

// ---------------- column-sum of a chunk of rows: out[chunk][c] = sum partial[r][c] ----------------
__global__ __launch_bounds__(256) void k_colsum(const float* __restrict__ partial,
                                                float* __restrict__ out, int W, int rpc) {
    int c = blockIdx.x*256 + threadIdx.x;
    if (c >= W) return;
    long r0 = (long)blockIdx.y * rpc;
    float s = 0.f;
    for (int r = 0; r < rpc; ++r) s += partial[(r0 + r)*W + c];
    out[(long)blockIdx.y*W + c] = s;
}

// ---------------- scale/shift from sums ----------------
__global__ __launch_bounds__(256) void k_bn_finalize(
    const float* __restrict__ sums, const float* __restrict__ g,
    const float* __restrict__ beta, float* __restrict__ ss, int O, float invCnt)
{
    int o = blockIdx.x*256 + threadIdx.x;
    if (o >= O) return;
    float mean = sums[o]*invCnt;
    float var  = sums[O + o]*invCnt - mean*mean;
    float sc = g[o] * rsqrtf(var + 1e-5f);
    ss[o] = sc;
    ss[O + o] = beta[o] - mean*sc;
}

// ---------------- apply BN + lrelu to hmax/hmin ----------------
__global__ __launch_bounds__(256) void k_edge_apply(
    const float* __restrict__ hmax, const float* __restrict__ hmin,
    const float* __restrict__ ss, float* __restrict__ out, int O)
{
    long i4 = (long)blockIdx.x*256 + threadIdx.x;   // float4 index
    int c4 = (int)(i4 & ((O >> 2) - 1)) << 2;
    float4 mx = *(const float4*)&hmax[i4*4];
    float4 mn = *(const float4*)&hmin[i4*4];
    float4 y;
    {
        float sc = ss[c4+0], sh = ss[O+c4+0];
        float v = fmaf(sc >= 0.f ? mx.x : mn.x, sc, sh); y.x = LRELU(v);
    }
    {
        float sc = ss[c4+1], sh = ss[O+c4+1];
        float v = fmaf(sc >= 0.f ? mx.y : mn.y, sc, sh); y.y = LRELU(v);
    }
    {
        float sc = ss[c4+2], sh = ss[O+c4+2];
        float v = fmaf(sc >= 0.f ? mx.z : mn.z, sc, sh); y.z = LRELU(v);
    }
    {
        float sc = ss[c4+3], sh = ss[O+c4+3];
        float v = fmaf(sc >= 0.f ? mx.w : mn.w, sc, sh); y.w = LRELU(v);
    }
    *(float4*)&out[i4*4] = y;
}

// ---------------- h5 stats partials (deterministic) ----------------
__global__ __launch_bounds__(256) void k_h5_stats_p(const float* __restrict__ h5,
                                                    float* __restrict__ partial) {
    int tid = threadIdx.x, bid = blockIdx.x;   // 2048 blocks, 16 points each
    int base = bid*16;
    float s[4] = {0,0,0,0}, s2[4] = {0,0,0,0};
    for (int i = 0; i < 16; ++i) {
        long row = (long)(base + i)*1024;
        #pragma unroll
        for (int cc = 0; cc < 4; ++cc) {
            float v = h5[row + cc*256 + tid];
            s[cc] += v; s2[cc] = fmaf(v, v, s2[cc]);
        }
    }
    #pragma unroll
    for (int cc = 0; cc < 4; ++cc) {
        partial[(long)bid*2048 + cc*256 + tid] = s[cc];
        partial[(long)bid*2048 + 1024 + cc*256 + tid] = s2[cc];
    }
}

// ---------------- f-reduction stage A: per 128-row chunk max/sum of y ----------------
__global__ __launch_bounds__(256) void k_reduce_fp(const float* __restrict__ h5,
                                                   const float* __restrict__ ss,
                                                   float* __restrict__ fpart) {
    int b = blockIdx.x, ch = blockIdx.y;
    int c = blockIdx.z*256 + threadIdx.x;
    float sc = ss[c], sh = ss[1024 + c];
    float mx = -INFINITY, sm = 0.f;
    int n0 = ch*128;
    for (int n = n0; n < n0 + 128; ++n) {
        float v = h5[((long)(b*2048 + n))*1024 + c];
        float y = fmaf(v, sc, sh); y = LRELU(y);
        mx = fmaxf(mx, y); sm += y;
    }
    fpart[((long)(b*16 + ch))*2048 + c] = mx;
    fpart[((long)(b*16 + ch))*2048 + 1024 + c] = sm;
}

// ---------------- f-reduction stage B ----------------
__global__ __launch_bounds__(256) void k_reduce_ff(const float* __restrict__ fpart,
                                                   float* __restrict__ f) {
    int b = blockIdx.x;
    int c = blockIdx.y*256 + threadIdx.x;
    float mx = -INFINITY, sm = 0.f;
    for (int ch = 0; ch < 16; ++ch) {
        mx = fmaxf(mx, fpart[((long)(b*16 + ch))*2048 + c]);
        sm += fpart[((long)(b*16 + ch))*2048 + 1024 + c];
    }
    f[(long)b*2048 + c] = mx;
    f[(long)b*2048 + 1024 + c] = sm * (1.f/2048.f);
}

// ---------------- small FC matmul: Y[b,j] = X[b,:].W[j,:] + bias ----------------
__global__ __launch_bounds__(256) void k_fc_mm(const float* __restrict__ X,
                                               const float* __restrict__ W,
                                               const float* __restrict__ bias,
                                               float* __restrict__ Y,
                                               int Kdim, int Ncol) {
    int t = blockIdx.x*256 + threadIdx.x;
    if (t >= 16*Ncol) return;
    int b = t / Ncol, j = t % Ncol;
    const float* xr = X + (long)b*Kdim;
    const float* wr = W + (long)j*Kdim;
    float s = 0.f;
    for (int k = 0; k < Kdim; k++) s = fmaf(xr[k], wr[k], s);
    Y[t] = s + (bias ? bias[j] : 0.f);
}

// ---------------- BN over batch axis (16) + lrelu ----------------
__global__ __launch_bounds__(256) void k_bn_rows(const float* __restrict__ X,
                                                 const float* __restrict__ g,
                                                 const float* __restrict__ be,
                                                 float* __restrict__ Y, int Ncol) {
    int j = blockIdx.x*256 + threadIdx.x;
    if (j >= Ncol) return;
    float s = 0.f, s2 = 0.f;
    for (int b = 0; b < 16; b++) { float v = X[b*Ncol + j]; s += v; s2 = fmaf(v, v, s2); }
    float mean = s*(1.f/16.f);
    float var  = s2*(1.f/16.f) - mean*mean;
    float sc = g[j]*rsqrtf(var + 1e-5f);
    float sh = be[j] - mean*sc;
    for (int b = 0; b < 16; b++) {
        float v = fmaf(X[b*Ncol + j], sc, sh);
        Y[b*Ncol + j] = LRELU(v);
    }
}

extern "C" void kernel_launch(void* const* d_in, const int* in_sizes, int n_in,
                              void* d_out, int out_size, void* d_ws, size_t ws_size,
                              hipStream_t stream) {
    const float* data = (const float*)d_in[0];
    const float* W1 = (const float*)d_in[1];  const float* g1 = (const float*)d_in[2];  const float* b1 = (const float*)d_in[3];
    const float* W2 = (const float*)d_in[4];  const float* g2 = (const float*)d_in[5];  const float* b2 = (const float*)d_in[6];
    const float* W3 = (const float*)d_in[7];  const float* g3 = (const float*)d_in[8];  const float* b3 = (const float*)d_in[9];
    const float* W4 = (const float*)d_in[10]; const float* g4 = (const float*)d_in[11]; const float* b4 = (const float*)d_in[12];
    const float* W5 = (const float*)d_in[13]; const float* g5 = (const float*)d_in[14]; const float* b5 = (const float*)d_in[15];
    const float* fc1W = (const float*)d_in[16]; const float* bn1g = (const float*)d_in[17]; const float* bn1b = (const float*)d_in[18];
    const float* fc2W = (const float*)d_in[19]; const float* fc2b = (const float*)d_in[20];
    const float* bn2g = (const float*)d_in[21]; const float* bn2b = (const float*)d_in[22];
    const float* fc3W = (const float*)d_in[23]; const float* fc3b = (const float*)d_in[24];

    void* wsym = nullptr;
    hipGetSymbolAddress(&wsym, HIP_SYMBOL(g_ws));
    char* w = (char*)wsym;
    size_t off = 0;
    auto alloc = [&](size_t bytes) { void* r = w + off; off += (bytes + 255) & ~size_t(255); return r; };
    float* S   = (float*)alloc(134217728);      // dist (8 batches) / h5 / hmax+hmin+partial
    float* x0  = (float*)alloc(393216);
    float* d1  = (float*)alloc(8388608);
    float* d2  = (float*)alloc(8388608);
    float* d3  = (float*)alloc(16777216);
    float* d4  = (float*)alloc(33554432);
    float* p   = (float*)alloc(33554432);
    float* q   = (float*)alloc(33554432);
    int*   idxb= (int*)  alloc(2621440);
    float* sqb = (float*)alloc(131072);
    float* Wd  = (float*)alloc(131072);
    float* sums= (float*)alloc(8192);
    float* ssb = (float*)alloc(8192);
    float* f   = (float*)alloc(131072);
    float* t1  = (float*)alloc(32768);
    float* a1  = (float*)alloc(32768);
    float* t2  = (float*)alloc(16384);
    float* a2  = (float*)alloc(16384);
    (void)ws_size; (void)n_in; (void)in_sizes; (void)out_size; (void)d_ws;

    // aliases inside S / dead buffers (live ranges don't overlap):
    float* hmaxb = S;                 // 32768*O <= 8.39M floats
    float* hminb = S + 8388608;
    float* partb = S + 16777216;      // 2048 x 2*O <= 1.05M floats
    float* part2 = S + 18874368;      // 32 x 2*O chunk sums
    float* h5par = d4;                // h5 stats partials (16 MB), d4 dead after cat-GEMM
    float* h5pt2 = d2;                // 32 x 2048 chunk sums, d2 dead after cat-GEMM
    float* fpart = d1;                // f-reduce partials (2 MB), d1 dead after cat-GEMM

    k_transpose_in<<<128, 256, 0, stream>>>(data, x0);

    auto layer = [&](const float* x, int C, int O, int lg2TPP, const float* W,
                     const float* g, const float* beta, float* out) {
        k_sqnorm<<<128, 256, 0, stream>>>(x, sqb, C);
        for (int ch = 0; ch < 2; ch++) {
            const float* xc = x + (long)ch*16384*C;
            k_gemm_nt<<<dim3(16,16,8), 256, 0, stream>>>(
                xc, C, (long)2048*C, xc, C, (long)2048*C,
                S, 2048, (long)2048*2048, C, 2048, 2, sqb + ch*16384, 2048);
            k_topk20<<<4096, 256, 0, stream>>>(S, idxb, ch*16384);
        }
        k_wdiff<<<(O*C + 255)/256, 256, 0, stream>>>(W, Wd, O, C);
        k_gemm_nt<<<dim3(256, (O+127)/128, 1), 256, 0, stream>>>(
            x, C, 0, W, 2*C, 0, p, O, 0, C, O, 0, nullptr, 0);
        k_gemm_nt<<<dim3(256, (O+127)/128, 1), 256, 0, stream>>>(
            x, C, 0, Wd, C, 0, q, O, 0, C, O, 0, nullptr, 0);
        k_edge_gather<<<2048, 256, 0, stream>>>(p, q, idxb, hmaxb, hminb, partb, O, lg2TPP);
        // two-stage deterministic column sum: 2048 rows -> 32 -> 1
        k_colsum<<<dim3((2*O + 255)/256, 32), 256, 0, stream>>>(partb, part2, 2*O, 64);
        k_colsum<<<dim3((2*O + 255)/256, 1),  256, 0, stream>>>(part2, sums,  2*O, 32);
        k_bn_finalize<<<(O+255)/256, 256, 0, stream>>>(sums, g, beta, ssb, O, 1.f/655360.f);
        k_edge_apply<<<32*O, 256, 0, stream>>>(hmaxb, hminb, ssb, out, O);
    };

    layer(x0, 3,   64,  4, W1, g1, b1, d1);
    layer(d1, 64,  64,  4, W2, g2, b2, d2);
    layer(d2, 64,  128, 5, W3, g3, b3, d3);
    layer(d3, 128, 256, 6, W4, g4, b4, d4);

    // fused h5 = cat(d1,d2,d3,d4) @ W5^T  -> S
    k_gemm_cat<<<dim3(256,8,1), 256, 0, stream>>>(d1, d2, d3, d4, W5, S);

    // h5 BN stats (deterministic two-stage) + fused BN+lrelu+max/mean reduce
    k_h5_stats_p<<<2048, 256, 0, stream>>>(S, h5par);
    k_colsum<<<dim3(8, 32), 256, 0, stream>>>(h5par, h5pt2, 2048, 64);
    k_colsum<<<dim3(8, 1),  256, 0, stream>>>(h5pt2, sums,  2048, 32);
    k_bn_finalize<<<4, 256, 0, stream>>>(sums, g5, b5, ssb, 1024, 1.f/32768.f);
    k_reduce_fp<<<dim3(16,16,4), 256, 0, stream>>>(S, ssb, fpart);
    k_reduce_ff<<<dim3(16,4), 256, 0, stream>>>(fpart, f);

    k_fc_mm<<<32, 256, 0, stream>>>(f,  fc1W, nullptr, t1, 2048, 512);
    k_bn_rows<<<2, 256, 0, stream>>>(t1, bn1g, bn1b, a1, 512);
    k_fc_mm<<<16, 256, 0, stream>>>(a1, fc2W, fc2b, t2, 512, 256);
    k_bn_rows<<<1, 256, 0, stream>>>(t2, bn2g, bn2b, a2, 256);
    k_fc_mm<<<3, 256, 0, stream>>>(a2, fc3W, fc3b, (float*)d_out, 256, 40);
}

// Round 6
// 2752.756 us; speedup vs baseline: 1.8182x; 1.0170x over previous
//
#include <hip/hip_runtime.h>
#include <math.h>

#define LRELU(x) ((x) >= 0.f ? (x) : 0.2f*(x))

// ---- static device scratch (285 MB): independent of harness ws_size ----
#define WS_FLOATS 71303168u
__device__ __align__(256) float g_ws[WS_FLOATS];

// ---------------- transpose (B,3,N) -> (B*N,3) ----------------
__global__ __launch_bounds__(256) void k_transpose_in(const float* __restrict__ data,
                                                      float* __restrict__ x0) {
    int i = blockIdx.x*256 + threadIdx.x;      // over B*N = 32768
    int b = i >> 11, n = i & 2047;
    #pragma unroll
    for (int c = 0; c < 3; c++)
        x0[(long)i*3 + c] = data[((long)b*3 + c)*2048 + n];
}

// ---------------- squared norms ----------------
__global__ __launch_bounds__(256) void k_sqnorm(const float* __restrict__ x,
                                                float* __restrict__ sq, int C) {
    int i = blockIdx.x*256 + threadIdx.x;      // over 32768 points
    const float* xr = x + (long)i*C;
    float s = 0.f;
    for (int c = 0; c < C; c++) s = fmaf(xr[c], xr[c], s);
    sq[i] = s;
}

// ---------------- fp32 GEMM: C[i,j] = sum_k A[i,k]*B[j,k] ----------------
// mode 0: store; mode 2: dist epilogue 2*acc - sq[i] - sq[j]
// B-fragment: split columns {tx*4, 64+tx*4} -> 16B lane stride = 2-way LDS
// aliasing (free, m136) instead of 32B stride (4-way conflict).
#define KC 8
__global__ __launch_bounds__(256) void k_gemm_nt(
    const float* __restrict__ A, int lda, long sAb,
    const float* __restrict__ B, int ldb, long sBb,
    float* __restrict__ Cm, int ldc, long sCb,
    int K, int Nj, int mode, const float* __restrict__ sq, int sqStride)
{
    __shared__ float As[KC][132];
    __shared__ float Bs[KC][132];
    int z = blockIdx.z;
    const float* Ab = A + (long)z*sAb;
    const float* Bb = B + (long)z*sBb;
    float* Cb = Cm + (long)z*sCb;
    int rowBase = blockIdx.x*128, colBase = blockIdx.y*128;
    int tid = threadIdx.x, tx = tid & 15, ty = tid >> 4;
    float acc[8][8] = {};
    for (int k0 = 0; k0 < K; k0 += KC) {
        #pragma unroll
        for (int l = 0; l < 4; l++) {
            int id = tid + l*256;
            int kk = id & 7, r = id >> 3;   // r in 0..127
            float av = 0.f, bv = 0.f;
            if (k0 + kk < K) {
                av = Ab[(long)(rowBase + r)*lda + k0 + kk];
                if (colBase + r < Nj)
                    bv = Bb[(long)(colBase + r)*ldb + k0 + kk];
            }
            As[kk][r] = av; Bs[kk][r] = bv;
        }
        __syncthreads();
        #pragma unroll
        for (int kk = 0; kk < KC; kk++) {
            float4 a0 = *(const float4*)&As[kk][ty*8];
            float4 a1 = *(const float4*)&As[kk][ty*8 + 4];
            float4 b0 = *(const float4*)&Bs[kk][tx*4];
            float4 b1 = *(const float4*)&Bs[kk][64 + tx*4];
            float a[8] = {a0.x,a0.y,a0.z,a0.w,a1.x,a1.y,a1.z,a1.w};
            float b[8] = {b0.x,b0.y,b0.z,b0.w,b1.x,b1.y,b1.z,b1.w};
            #pragma unroll
            for (int i = 0; i < 8; i++)
                #pragma unroll
                for (int j = 0; j < 8; j++)
                    acc[i][j] = fmaf(a[i], b[j], acc[i][j]);
        }
        __syncthreads();
    }
    const float* sqz = sq + (long)z*sqStride;  // only dereferenced in mode 2
    #pragma unroll
    for (int i = 0; i < 8; i++) {
        int r = rowBase + ty*8 + i;
        float sqr = (mode == 2) ? sqz[r] : 0.f;
        #pragma unroll
        for (int half = 0; half < 2; half++) {
            int c = colBase + half*64 + tx*4;
            int jb = half*4;
            if (c + 3 < Nj) {
                float4 v;
                v.x = acc[i][jb+0]; v.y = acc[i][jb+1];
                v.z = acc[i][jb+2]; v.w = acc[i][jb+3];
                if (mode == 2) {
                    v.x = 2.f*v.x - sqr - sqz[c+0];
                    v.y = 2.f*v.y - sqr - sqz[c+1];
                    v.z = 2.f*v.z - sqr - sqz[c+2];
                    v.w = 2.f*v.w - sqr - sqz[c+3];
                }
                *(float4*)&Cb[(long)r*ldc + c] = v;
            } else {
                #pragma unroll
                for (int j = 0; j < 4; j++) {
                    int c2 = c + j;
                    if (c2 >= Nj) continue;
                    float v = acc[i][jb+j];
                    if (mode == 2) v = 2.f*v - sqr - sqz[c2];
                    Cb[(long)r*ldc + c2] = v;
                }
            }
        }
    }
}

// ---------------- fused cat(d1,d2,d3,d4) @ W5^T   (K=512, out 32768x1024) ----------------
__global__ __launch_bounds__(256) void k_gemm_cat(
    const float* __restrict__ d1, const float* __restrict__ d2,
    const float* __restrict__ d3, const float* __restrict__ d4,
    const float* __restrict__ W5, float* __restrict__ Cm)
{
    __shared__ float As[KC][132];
    __shared__ float Bs[KC][132];
    int rowBase = blockIdx.x*128, colBase = blockIdx.y*128;
    int tid = threadIdx.x, tx = tid & 15, ty = tid >> 4;
    float acc[8][8] = {};
    for (int k0 = 0; k0 < 512; k0 += KC) {
        const float* Ab; int lda_, koff;
        if (k0 < 64)       { Ab = d1; lda_ = 64;  koff = k0; }
        else if (k0 < 128) { Ab = d2; lda_ = 64;  koff = k0 - 64; }
        else if (k0 < 256) { Ab = d3; lda_ = 128; koff = k0 - 128; }
        else               { Ab = d4; lda_ = 256; koff = k0 - 256; }
        #pragma unroll
        for (int l = 0; l < 4; l++) {
            int id = tid + l*256;
            int kk = id & 7, r = id >> 3;
            As[kk][r] = Ab[(long)(rowBase + r)*lda_ + koff + kk];
            Bs[kk][r] = W5[(long)(colBase + r)*512 + k0 + kk];
        }
        __syncthreads();
        #pragma unroll
        for (int kk = 0; kk < KC; kk++) {
            float4 a0 = *(const float4*)&As[kk][ty*8];
            float4 a1 = *(const float4*)&As[kk][ty*8 + 4];
            float4 b0 = *(const float4*)&Bs[kk][tx*4];
            float4 b1 = *(const float4*)&Bs[kk][64 + tx*4];
            float a[8] = {a0.x,a0.y,a0.z,a0.w,a1.x,a1.y,a1.z,a1.w};
            float b[8] = {b0.x,b0.y,b0.z,b0.w,b1.x,b1.y,b1.z,b1.w};
            #pragma unroll
            for (int i = 0; i < 8; i++)
                #pragma unroll
                for (int j = 0; j < 8; j++)
                    acc[i][j] = fmaf(a[i], b[j], acc[i][j]);
        }
        __syncthreads();
    }
    #pragma unroll
    for (int i = 0; i < 8; i++) {
        long r = rowBase + ty*8 + i;
        #pragma unroll
        for (int half = 0; half < 2; half++) {
            int c = colBase + half*64 + tx*4;
            int jb = half*4;
            float4 v;
            v.x = acc[i][jb+0]; v.y = acc[i][jb+1];
            v.z = acc[i][jb+2]; v.w = acc[i][jb+3];
            *(float4*)&Cm[r*1024 + c] = v;
        }
    }
}

// ---------------- top-20 per row (value desc, index asc ties) ----------------
__global__ __launch_bounds__(256) void k_topk20(const float* __restrict__ dist,
                                                int* __restrict__ idxOut, int rowOffset)
{
    __shared__ float lds[4][2048];
    int wave = threadIdx.x >> 6, lane = threadIdx.x & 63;
    int row = blockIdx.x*4 + wave;
    const float* dr = dist + (long)row*2048;
    float* L = lds[wave];
    for (int i = 0; i < 32; i++) L[i*64 + lane] = dr[i*64 + lane];
    __syncthreads();
    int* out = idxOut + (long)(rowOffset + row)*20;
    for (int it = 0; it < 20; it++) {
        float bv = -INFINITY; int bi = 0x7fffffff;
        for (int i = 0; i < 32; i++) {
            float v = L[i*64 + lane];
            if (v > bv) { bv = v; bi = i*64 + lane; }
        }
        #pragma unroll
        for (int s = 32; s > 0; s >>= 1) {
            float ov = __shfl_xor(bv, s);
            int   oi = __shfl_xor(bi, s);
            if (ov > bv || (ov == bv && oi < bi)) { bv = ov; bi = oi; }
        }
        if (lane == 0) out[it] = bi;
        if (lane == (bi & 63)) L[bi] = -INFINITY;
    }
}

// ---------------- Wd = W[:,C:] - W[:,:C] ----------------
__global__ __launch_bounds__(256) void k_wdiff(const float* __restrict__ W,
                                               float* __restrict__ Wd, int O, int C) {
    int i = blockIdx.x*256 + threadIdx.x;
    if (i >= O*C) return;
    int o = i / C, c = i % C;
    Wd[o*C + c] = W[(long)o*2*C + C + c] - W[(long)o*2*C + c];
}

// ---------------- fused gather: hmax/hmin per (pt,c) + block stats partials ----------------
__global__ __launch_bounds__(256) void k_edge_gather(
    const float* __restrict__ p, const float* __restrict__ q,
    const int* __restrict__ idx,
    float* __restrict__ hmax, float* __restrict__ hmin,
    float* __restrict__ partial, int O, int lg2TPP)
{
    __shared__ float ldsS[1024];
    __shared__ float ldsS2[1024];
    int tid = threadIdx.x;
    int TPP = O >> 2;                    // threads per point
    int c4 = (tid & (TPP - 1)) << 2;
    int sub = tid >> lg2TPP;
    int nsub = 256 >> lg2TPP;            // points in flight
    int wg = blockIdx.x;
    int logical = (wg & 7)*256 + (wg >> 3);   // XCD swizzle: 2 batches per XCD
    int base = logical*16;
    float4 s = {0,0,0,0}, s2 = {0,0,0,0};
    int iters = 16 / nsub;
    for (int it = 0; it < iters; ++it) {
        int pt = base + sub + it*nsub;
        int bb = (pt >> 11) << 11;
        const int* ir = idx + (long)pt*20;
        float4 qv = *(const float4*)&q[(long)pt*O + c4];
        float4 mx = {-INFINITY,-INFINITY,-INFINITY,-INFINITY};
        float4 mn = { INFINITY, INFINITY, INFINITY, INFINITY};
        for (int k = 0; k < 20; ++k) {
            int m = ir[k];
            float4 pv = *(const float4*)&p[(long)(bb + m)*O + c4];
            float4 h;
            h.x = pv.x + qv.x; h.y = pv.y + qv.y;
            h.z = pv.z + qv.z; h.w = pv.w + qv.w;
            mx.x = fmaxf(mx.x, h.x); mx.y = fmaxf(mx.y, h.y);
            mx.z = fmaxf(mx.z, h.z); mx.w = fmaxf(mx.w, h.w);
            mn.x = fminf(mn.x, h.x); mn.y = fminf(mn.y, h.y);
            mn.z = fminf(mn.z, h.z); mn.w = fminf(mn.w, h.w);
            s.x += h.x; s.y += h.y; s.z += h.z; s.w += h.w;
            s2.x = fmaf(h.x, h.x, s2.x); s2.y = fmaf(h.y, h.y, s2.y);
            s2.z = fmaf(h.z, h.z, s2.z); s2.w = fmaf(h.w, h.w, s2.w);
        }
        *(float4*)&hmax[(long)pt*O + c4] = mx;
        *(float4*)&hmin[(long)pt*O + c4] = mn;
    }
    *(float4*)&ldsS [sub*O + c4] = s;
    *(float4*)&ldsS2[sub*O + c4] = s2;
    __syncthreads();
    if (tid < O) {
        float a = 0.f, b = 0.f;
        for (int u = 0; u < nsub; ++u) { a += ldsS[u*O + tid]; b += ldsS2[u*O + tid]; }
        partial[(long)wg*2*O + tid] = a;
        partial[(long)wg*2*O + O + tid] = b;
    }
}

// ---------------- column-sum of a chunk of rows ----------------
__global__ __launch_bounds__(256) void k_colsum(const float* __restrict__ partial,
                                                float* __restrict__ out, int W, int rpc) {
    int c = blockIdx.x*256 + threadIdx.x;
    if (c >= W) return;
    long r0 = (long)blockIdx.y * rpc;
    float s = 0.f;
    for (int r = 0; r < rpc; ++r) s += partial[(r0 + r)*W + c];
    out[(long)blockIdx.y*W + c] = s;
}

// ---------------- scale/shift from sums ----------------
__global__ __launch_bounds__(256) void k_bn_finalize(
    const float* __restrict__ sums, const float* __restrict__ g,
    const float* __restrict__ beta, float* __restrict__ ss, int O, float invCnt)
{
    int o = blockIdx.x*256 + threadIdx.x;
    if (o >= O) return;
    float mean = sums[o]*invCnt;
    float var  = sums[O + o]*invCnt - mean*mean;
    float sc = g[o] * rsqrtf(var + 1e-5f);
    ss[o] = sc;
    ss[O + o] = beta[o] - mean*sc;
}

// ---------------- apply BN + lrelu to hmax/hmin ----------------
__global__ __launch_bounds__(256) void k_edge_apply(
    const float* __restrict__ hmax, const float* __restrict__ hmin,
    const float* __restrict__ ss, float* __restrict__ out, int O)
{
    long i4 = (long)blockIdx.x*256 + threadIdx.x;   // float4 index
    int c4 = (int)(i4 & ((O >> 2) - 1)) << 2;
    float4 mx = *(const float4*)&hmax[i4*4];
    float4 mn = *(const float4*)&hmin[i4*4];
    float4 y;
    {
        float sc = ss[c4+0], sh = ss[O+c4+0];
        float v = fmaf(sc >= 0.f ? mx.x : mn.x, sc, sh); y.x = LRELU(v);
    }
    {
        float sc = ss[c4+1], sh = ss[O+c4+1];
        float v = fmaf(sc >= 0.f ? mx.y : mn.y, sc, sh); y.y = LRELU(v);
    }
    {
        float sc = ss[c4+2], sh = ss[O+c4+2];
        float v = fmaf(sc >= 0.f ? mx.z : mn.z, sc, sh); y.z = LRELU(v);
    }
    {
        float sc = ss[c4+3], sh = ss[O+c4+3];
        float v = fmaf(sc >= 0.f ? mx.w : mn.w, sc, sh); y.w = LRELU(v);
    }
    *(float4*)&out[i4*4] = y;
}

// ---------------- h5 stats partials (deterministic) ----------------
__global__ __launch_bounds__(256) void k_h5_stats_p(const float* __restrict__ h5,
                                                    float* __restrict__ partial) {
    int tid = threadIdx.x, bid = blockIdx.x;   // 2048 blocks, 16 points each
    int base = bid*16;
    float s[4] = {0,0,0,0}, s2[4] = {0,0,0,0};
    for (int i = 0; i < 16; ++i) {
        long row = (long)(base + i)*1024;
        #pragma unroll
        for (int cc = 0; cc < 4; ++cc) {
            float v = h5[row + cc*256 + tid];
            s[cc] += v; s2[cc] = fmaf(v, v, s2[cc]);
        }
    }
    #pragma unroll
    for (int cc = 0; cc < 4; ++cc) {
        partial[(long)bid*2048 + cc*256 + tid] = s[cc];
        partial[(long)bid*2048 + 1024 + cc*256 + tid] = s2[cc];
    }
}

// ---------------- f-reduction stage A ----------------
__global__ __launch_bounds__(256) void k_reduce_fp(const float* __restrict__ h5,
                                                   const float* __restrict__ ss,
                                                   float* __restrict__ fpart) {
    int b = blockIdx.x, ch = blockIdx.y;
    int c = blockIdx.z*256 + threadIdx.x;
    float sc = ss[c], sh = ss[1024 + c];
    float mx = -INFINITY, sm = 0.f;
    int n0 = ch*128;
    for (int n = n0; n < n0 + 128; ++n) {
        float v = h5[((long)(b*2048 + n))*1024 + c];
        float y = fmaf(v, sc, sh); y = LRELU(y);
        mx = fmaxf(mx, y); sm += y;
    }
    fpart[((long)(b*16 + ch))*2048 + c] = mx;
    fpart[((long)(b*16 + ch))*2048 + 1024 + c] = sm;
}

// ---------------- f-reduction stage B ----------------
__global__ __launch_bounds__(256) void k_reduce_ff(const float* __restrict__ fpart,
                                                   float* __restrict__ f) {
    int b = blockIdx.x;
    int c = blockIdx.y*256 + threadIdx.x;
    float mx = -INFINITY, sm = 0.f;
    for (int ch = 0; ch < 16; ++ch) {
        mx = fmaxf(mx, fpart[((long)(b*16 + ch))*2048 + c]);
        sm += fpart[((long)(b*16 + ch))*2048 + 1024 + c];
    }
    f[(long)b*2048 + c] = mx;
    f[(long)b*2048 + 1024 + c] = sm * (1.f/2048.f);
}

// ---------------- small FC matmul ----------------
__global__ __launch_bounds__(256) void k_fc_mm(const float* __restrict__ X,
                                               const float* __restrict__ W,
                                               const float* __restrict__ bias,
                                               float* __restrict__ Y,
                                               int Kdim, int Ncol) {
    int t = blockIdx.x*256 + threadIdx.x;
    if (t >= 16*Ncol) return;
    int b = t / Ncol, j = t % Ncol;
    const float* xr = X + (long)b*Kdim;
    const float* wr = W + (long)j*Kdim;
    float s = 0.f;
    for (int k = 0; k < Kdim; k++) s = fmaf(xr[k], wr[k], s);
    Y[t] = s + (bias ? bias[j] : 0.f);
}

// ---------------- BN over batch axis (16) + lrelu ----------------
__global__ __launch_bounds__(256) void k_bn_rows(const float* __restrict__ X,
                                                 const float* __restrict__ g,
                                                 const float* __restrict__ be,
                                                 float* __restrict__ Y, int Ncol) {
    int j = blockIdx.x*256 + threadIdx.x;
    if (j >= Ncol) return;
    float s = 0.f, s2 = 0.f;
    for (int b = 0; b < 16; b++) { float v = X[b*Ncol + j]; s += v; s2 = fmaf(v, v, s2); }
    float mean = s*(1.f/16.f);
    float var  = s2*(1.f/16.f) - mean*mean;
    float sc = g[j]*rsqrtf(var + 1e-5f);
    float sh = be[j] - mean*sc;
    for (int b = 0; b < 16; b++) {
        float v = fmaf(X[b*Ncol + j], sc, sh);
        Y[b*Ncol + j] = LRELU(v);
    }
}

extern "C" void kernel_launch(void* const* d_in, const int* in_sizes, int n_in,
                              void* d_out, int out_size, void* d_ws, size_t ws_size,
                              hipStream_t stream) {
    const float* data = (const float*)d_in[0];
    const float* W1 = (const float*)d_in[1];  const float* g1 = (const float*)d_in[2];  const float* b1 = (const float*)d_in[3];
    const float* W2 = (const float*)d_in[4];  const float* g2 = (const float*)d_in[5];  const float* b2 = (const float*)d_in[6];
    const float* W3 = (const float*)d_in[7];  const float* g3 = (const float*)d_in[8];  const float* b3 = (const float*)d_in[9];
    const float* W4 = (const float*)d_in[10]; const float* g4 = (const float*)d_in[11]; const float* b4 = (const float*)d_in[12];
    const float* W5 = (const float*)d_in[13]; const float* g5 = (const float*)d_in[14]; const float* b5 = (const float*)d_in[15];
    const float* fc1W = (const float*)d_in[16]; const float* bn1g = (const float*)d_in[17]; const float* bn1b = (const float*)d_in[18];
    const float* fc2W = (const float*)d_in[19]; const float* fc2b = (const float*)d_in[20];
    const float* bn2g = (const float*)d_in[21]; const float* bn2b = (const float*)d_in[22];
    const float* fc3W = (const float*)d_in[23]; const float* fc3b = (const float*)d_in[24];

    void* wsym = nullptr;
    hipGetSymbolAddress(&wsym, HIP_SYMBOL(g_ws));
    char* w = (char*)wsym;
    size_t off = 0;
    auto alloc = [&](size_t bytes) { void* r = w + off; off += (bytes + 255) & ~size_t(255); return r; };
    float* S   = (float*)alloc(134217728);      // dist (8 batches) / h5 / hmax+hmin+partial
    float* x0  = (float*)alloc(393216);
    float* d1  = (float*)alloc(8388608);
    float* d2  = (float*)alloc(8388608);
    float* d3  = (float*)alloc(16777216);
    float* d4  = (float*)alloc(33554432);
    float* p   = (float*)alloc(33554432);
    float* q   = (float*)alloc(33554432);
    int*   idxb= (int*)  alloc(2621440);
    float* sqb = (float*)alloc(131072);
    float* Wd  = (float*)alloc(131072);
    float* sums= (float*)alloc(8192);
    float* ssb = (float*)alloc(8192);
    float* f   = (float*)alloc(131072);
    float* t1  = (float*)alloc(32768);
    float* a1  = (float*)alloc(32768);
    float* t2  = (float*)alloc(16384);
    float* a2  = (float*)alloc(16384);
    (void)ws_size; (void)n_in; (void)in_sizes; (void)out_size; (void)d_ws;

    // aliases inside S / dead buffers (live ranges don't overlap):
    float* hmaxb = S;                 // 32768*O <= 8.39M floats
    float* hminb = S + 8388608;
    float* partb = S + 16777216;      // 2048 x 2*O <= 1.05M floats
    float* part2 = S + 18874368;      // 32 x 2*O chunk sums
    float* h5par = d4;                // h5 stats partials (16 MB), d4 dead after cat-GEMM
    float* h5pt2 = d2;                // 32 x 2048 chunk sums, d2 dead after cat-GEMM
    float* fpart = d1;                // f-reduce partials (2 MB), d1 dead after cat-GEMM

    k_transpose_in<<<128, 256, 0, stream>>>(data, x0);

    auto layer = [&](const float* x, int C, int O, int lg2TPP, const float* W,
                     const float* g, const float* beta, float* out) {
        k_sqnorm<<<128, 256, 0, stream>>>(x, sqb, C);
        for (int ch = 0; ch < 2; ch++) {
            const float* xc = x + (long)ch*16384*C;
            k_gemm_nt<<<dim3(16,16,8), 256, 0, stream>>>(
                xc, C, (long)2048*C, xc, C, (long)2048*C,
                S, 2048, (long)2048*2048, C, 2048, 2, sqb + ch*16384, 2048);
            k_topk20<<<4096, 256, 0, stream>>>(S, idxb, ch*16384);
        }
        k_wdiff<<<(O*C + 255)/256, 256, 0, stream>>>(W, Wd, O, C);
        k_gemm_nt<<<dim3(256, (O+127)/128, 1), 256, 0, stream>>>(
            x, C, 0, W, 2*C, 0, p, O, 0, C, O, 0, nullptr, 0);
        k_gemm_nt<<<dim3(256, (O+127)/128, 1), 256, 0, stream>>>(
            x, C, 0, Wd, C, 0, q, O, 0, C, O, 0, nullptr, 0);
        k_edge_gather<<<2048, 256, 0, stream>>>(p, q, idxb, hmaxb, hminb, partb, O, lg2TPP);
        // two-stage deterministic column sum: 2048 rows -> 32 -> 1
        k_colsum<<<dim3((2*O + 255)/256, 32), 256, 0, stream>>>(partb, part2, 2*O, 64);
        k_colsum<<<dim3((2*O + 255)/256, 1),  256, 0, stream>>>(part2, sums,  2*O, 32);
        k_bn_finalize<<<(O+255)/256, 256, 0, stream>>>(sums, g, beta, ssb, O, 1.f/655360.f);
        k_edge_apply<<<32*O, 256, 0, stream>>>(hmaxb, hminb, ssb, out, O);
    };

    layer(x0, 3,   64,  4, W1, g1, b1, d1);
    layer(d1, 64,  64,  4, W2, g2, b2, d2);
    layer(d2, 64,  128, 5, W3, g3, b3, d3);
    layer(d3, 128, 256, 6, W4, g4, b4, d4);

    // fused h5 = cat(d1,d2,d3,d4) @ W5^T  -> S
    k_gemm_cat<<<dim3(256,8,1), 256, 0, stream>>>(d1, d2, d3, d4, W5, S);

    // h5 BN stats (deterministic two-stage) + fused BN+lrelu+max/mean reduce
    k_h5_stats_p<<<2048, 256, 0, stream>>>(S, h5par);
    k_colsum<<<dim3(8, 32), 256, 0, stream>>>(h5par, h5pt2, 2048, 64);
    k_colsum<<<dim3(8, 1),  256, 0, stream>>>(h5pt2, sums,  2048, 32);
    k_bn_finalize<<<4, 256, 0, stream>>>(sums, g5, b5, ssb, 1024, 1.f/32768.f);
    k_reduce_fp<<<dim3(16,16,4), 256, 0, stream>>>(S, ssb, fpart);
    k_reduce_ff<<<dim3(16,4), 256, 0, stream>>>(fpart, f);

    k_fc_mm<<<32, 256, 0, stream>>>(f,  fc1W, nullptr, t1, 2048, 512);
    k_bn_rows<<<2, 256, 0, stream>>>(t1, bn1g, bn1b, a1, 512);
    k_fc_mm<<<16, 256, 0, stream>>>(a1, fc2W, fc2b, t2, 512, 256);
    k_bn_rows<<<1, 256, 0, stream>>>(t2, bn2g, bn2b, a2, 256);
    k_fc_mm<<<3, 256, 0, stream>>>(a2, fc3W, fc3b, (float*)d_out, 256, 40);
}

// Round 7
// 2398.264 us; speedup vs baseline: 2.0869x; 1.1478x over previous
//
#include <hip/hip_runtime.h>
#include <math.h>

#define LRELU(x) ((x) >= 0.f ? (x) : 0.2f*(x))

typedef _Float16 f16;
typedef f16 f16x8 __attribute__((ext_vector_type(8)));
typedef f16 f16x4 __attribute__((ext_vector_type(4)));
typedef float f32x4 __attribute__((ext_vector_type(4)));

// ---- static device scratch (312 MB): independent of harness ws_size ----
#define WS_FLOATS 78000000u
__device__ __align__(256) float g_ws[WS_FLOATS];

// ---------------- transpose (B,3,N) -> (B*N,3) ----------------
__global__ __launch_bounds__(256) void k_transpose_in(const float* __restrict__ data,
                                                      float* __restrict__ x0) {
    int i = blockIdx.x*256 + threadIdx.x;      // over B*N = 32768
    int b = i >> 11, n = i & 2047;
    #pragma unroll
    for (int c = 0; c < 3; c++)
        x0[(long)i*3 + c] = data[((long)b*3 + c)*2048 + n];
}

// ---------------- squared norms ----------------
__global__ __launch_bounds__(256) void k_sqnorm(const float* __restrict__ x,
                                                float* __restrict__ sq, int C) {
    int i = blockIdx.x*256 + threadIdx.x;      // over 32768 points
    const float* xr = x + (long)i*C;
    float s = 0.f;
    for (int c = 0; c < C; c++) s = fmaf(xr[c], xr[c], s);
    sq[i] = s;
}

// ---------------- fp32 GEMM: C[i,j] = sum_k A[i,k]*B[j,k] ----------------
// mode 0: store; mode 2: dist epilogue 2*acc - sq[i] - sq[j]
#define KC 8
__global__ __launch_bounds__(256) void k_gemm_nt(
    const float* __restrict__ A, int lda, long sAb,
    const float* __restrict__ B, int ldb, long sBb,
    float* __restrict__ Cm, int ldc, long sCb,
    int K, int Nj, int mode, const float* __restrict__ sq, int sqStride)
{
    __shared__ float As[KC][132];
    __shared__ float Bs[KC][132];
    int z = blockIdx.z;
    const float* Ab = A + (long)z*sAb;
    const float* Bb = B + (long)z*sBb;
    float* Cb = Cm + (long)z*sCb;
    int rowBase = blockIdx.x*128, colBase = blockIdx.y*128;
    int tid = threadIdx.x, tx = tid & 15, ty = tid >> 4;
    float acc[8][8] = {};
    for (int k0 = 0; k0 < K; k0 += KC) {
        #pragma unroll
        for (int l = 0; l < 4; l++) {
            int id = tid + l*256;
            int kk = id & 7, r = id >> 3;   // r in 0..127
            float av = 0.f, bv = 0.f;
            if (k0 + kk < K) {
                av = Ab[(long)(rowBase + r)*lda + k0 + kk];
                if (colBase + r < Nj)
                    bv = Bb[(long)(colBase + r)*ldb + k0 + kk];
            }
            As[kk][r] = av; Bs[kk][r] = bv;
        }
        __syncthreads();
        #pragma unroll
        for (int kk = 0; kk < KC; kk++) {
            float4 a0 = *(const float4*)&As[kk][ty*8];
            float4 a1 = *(const float4*)&As[kk][ty*8 + 4];
            float4 b0 = *(const float4*)&Bs[kk][tx*4];
            float4 b1 = *(const float4*)&Bs[kk][64 + tx*4];
            float a[8] = {a0.x,a0.y,a0.z,a0.w,a1.x,a1.y,a1.z,a1.w};
            float b[8] = {b0.x,b0.y,b0.z,b0.w,b1.x,b1.y,b1.z,b1.w};
            #pragma unroll
            for (int i = 0; i < 8; i++)
                #pragma unroll
                for (int j = 0; j < 8; j++)
                    acc[i][j] = fmaf(a[i], b[j], acc[i][j]);
        }
        __syncthreads();
    }
    const float* sqz = sq + (long)z*sqStride;  // only dereferenced in mode 2
    #pragma unroll
    for (int i = 0; i < 8; i++) {
        int r = rowBase + ty*8 + i;
        float sqr = (mode == 2) ? sqz[r] : 0.f;
        #pragma unroll
        for (int half = 0; half < 2; half++) {
            int c = colBase + half*64 + tx*4;
            int jb = half*4;
            if (c + 3 < Nj) {
                float4 v;
                v.x = acc[i][jb+0]; v.y = acc[i][jb+1];
                v.z = acc[i][jb+2]; v.w = acc[i][jb+3];
                if (mode == 2) {
                    v.x = 2.f*v.x - sqr - sqz[c+0];
                    v.y = 2.f*v.y - sqr - sqz[c+1];
                    v.z = 2.f*v.z - sqr - sqz[c+2];
                    v.w = 2.f*v.w - sqr - sqz[c+3];
                }
                *(float4*)&Cb[(long)r*ldc + c] = v;
            } else {
                #pragma unroll
                for (int j = 0; j < 4; j++) {
                    int c2 = c + j;
                    if (c2 >= Nj) continue;
                    float v = acc[i][jb+j];
                    if (mode == 2) v = 2.f*v - sqr - sqz[c2];
                    Cb[(long)r*ldc + c2] = v;
                }
            }
        }
    }
}

// ---------------- fp16 MFMA GEMM: C[m][n] = sum_k A[m][k]*B[n][k] ----------------
// A [M][lda] f16, B [N][ldb] f16, C [M][ldc] f32. Block tile 128x128, 4 waves
// 2x2, wave tile 64x64 = 4x4 subtiles of 16x16, K-step 32 (one mfma K).
__global__ __launch_bounds__(256) void k_gemm_mfma_nt(
    const f16* __restrict__ A, int lda,
    const f16* __restrict__ Bm, int ldb,
    float* __restrict__ Cm, int ldc, int K)
{
    __shared__ f16 As[128][40];   // pad to 40 halves (80 B) -> 2-way bank aliasing (free)
    __shared__ f16 Bs[128][40];
    int t = threadIdx.x;
    int rowBase = blockIdx.x*128, colBase = blockIdx.y*128;
    int wave = t >> 6, l = t & 63;
    int wrow = (wave >> 1)*64, wcol = (wave & 1)*64;
    int lr = l & 15, kg = l >> 4;
    int sr = t >> 1, seg = (t & 1)*16;   // staging: row 0..127, 16-half segment

    f32x4 acc[4][4] = {};
    for (int k0 = 0; k0 < K; k0 += 32) {
        const f16* ga = A  + (long)(rowBase + sr)*lda + k0 + seg;
        const f16* gb = Bm + (long)(colBase + sr)*ldb + k0 + seg;
        uint4 a0 = *(const uint4*)ga;
        uint4 a1 = *(const uint4*)(ga + 8);
        uint4 b0 = *(const uint4*)gb;
        uint4 b1 = *(const uint4*)(gb + 8);
        *(uint4*)&As[sr][seg]     = a0;
        *(uint4*)&As[sr][seg + 8] = a1;
        *(uint4*)&Bs[sr][seg]     = b0;
        *(uint4*)&Bs[sr][seg + 8] = b1;
        __syncthreads();
        f16x8 af[4], bf[4];
        #pragma unroll
        for (int i = 0; i < 4; i++) af[i] = *(const f16x8*)&As[wrow + i*16 + lr][kg*8];
        #pragma unroll
        for (int j = 0; j < 4; j++) bf[j] = *(const f16x8*)&Bs[wcol + j*16 + lr][kg*8];
        #pragma unroll
        for (int i = 0; i < 4; i++)
            #pragma unroll
            for (int j = 0; j < 4; j++)
                acc[i][j] = __builtin_amdgcn_mfma_f32_16x16x32_f16(af[i], bf[j], acc[i][j], 0, 0, 0);
        __syncthreads();
    }
    // D mapping (m89, dtype-independent): col = lane&15, row = (lane>>4)*4 + reg
    #pragma unroll
    for (int i = 0; i < 4; i++) {
        #pragma unroll
        for (int j = 0; j < 4; j++) {
            int row = rowBase + wrow + i*16 + kg*4;
            int col = colBase + wcol + j*16 + lr;
            #pragma unroll
            for (int r2 = 0; r2 < 4; r2++)
                Cm[(long)(row + r2)*ldc + col] = acc[i][j][r2];
        }
    }
}

// ---------------- fp32 -> fp16 elementwise ----------------
__global__ __launch_bounds__(256) void k_cvt_f16(const float* __restrict__ in,
                                                 f16* __restrict__ out, int n) {
    int i = blockIdx.x*256 + threadIdx.x;
    if (i < n) out[i] = (f16)in[i];
}

// ---------------- top-20 per row (value desc, index asc ties) ----------------
__global__ __launch_bounds__(256) void k_topk20(const float* __restrict__ dist,
                                                int* __restrict__ idxOut, int rowOffset)
{
    __shared__ float lds[4][2048];
    int wave = threadIdx.x >> 6, lane = threadIdx.x & 63;
    int row = blockIdx.x*4 + wave;
    const float* dr = dist + (long)row*2048;
    float* L = lds[wave];
    for (int i = 0; i < 32; i++) L[i*64 + lane] = dr[i*64 + lane];
    __syncthreads();
    int* out = idxOut + (long)(rowOffset + row)*20;
    for (int it = 0; it < 20; it++) {
        float bv = -INFINITY; int bi = 0x7fffffff;
        for (int i = 0; i < 32; i++) {
            float v = L[i*64 + lane];
            if (v > bv) { bv = v; bi = i*64 + lane; }
        }
        #pragma unroll
        for (int s = 32; s > 0; s >>= 1) {
            float ov = __shfl_xor(bv, s);
            int   oi = __shfl_xor(bi, s);
            if (ov > bv || (ov == bv && oi < bi)) { bv = ov; bi = oi; }
        }
        if (lane == 0) out[it] = bi;
        if (lane == (bi & 63)) L[bi] = -INFINITY;
    }
}

// ---------------- Wd = W[:,C:] - W[:,:C] ----------------
__global__ __launch_bounds__(256) void k_wdiff(const float* __restrict__ W,
                                               float* __restrict__ Wd, int O, int C) {
    int i = blockIdx.x*256 + threadIdx.x;
    if (i >= O*C) return;
    int o = i / C, c = i % C;
    Wd[o*C + c] = W[(long)o*2*C + C + c] - W[(long)o*2*C + c];
}

// ---------------- fused gather: hmax/hmin per (pt,c) + block stats partials ----------------
__global__ __launch_bounds__(256) void k_edge_gather(
    const float* __restrict__ p, const float* __restrict__ q,
    const int* __restrict__ idx,
    float* __restrict__ hmax, float* __restrict__ hmin,
    float* __restrict__ partial, int O, int lg2TPP)
{
    __shared__ float ldsS[1024];
    __shared__ float ldsS2[1024];
    int tid = threadIdx.x;
    int TPP = O >> 2;                    // threads per point
    int c4 = (tid & (TPP - 1)) << 2;
    int sub = tid >> lg2TPP;
    int nsub = 256 >> lg2TPP;            // points in flight
    int wg = blockIdx.x;
    int logical = (wg & 7)*256 + (wg >> 3);   // XCD swizzle: 2 batches per XCD
    int base = logical*16;
    float4 s = {0,0,0,0}, s2 = {0,0,0,0};
    int iters = 16 / nsub;
    for (int it = 0; it < iters; ++it) {
        int pt = base + sub + it*nsub;
        int bb = (pt >> 11) << 11;
        const int* ir = idx + (long)pt*20;
        float4 qv = *(const float4*)&q[(long)pt*O + c4];
        float4 mx = {-INFINITY,-INFINITY,-INFINITY,-INFINITY};
        float4 mn = { INFINITY, INFINITY, INFINITY, INFINITY};
        for (int k = 0; k < 20; ++k) {
            int m = ir[k];
            float4 pv = *(const float4*)&p[(long)(bb + m)*O + c4];
            float4 h;
            h.x = pv.x + qv.x; h.y = pv.y + qv.y;
            h.z = pv.z + qv.z; h.w = pv.w + qv.w;
            mx.x = fmaxf(mx.x, h.x); mx.y = fmaxf(mx.y, h.y);
            mx.z = fmaxf(mx.z, h.z); mx.w = fmaxf(mx.w, h.w);
            mn.x = fminf(mn.x, h.x); mn.y = fminf(mn.y, h.y);
            mn.z = fminf(mn.z, h.z); mn.w = fminf(mn.w, h.w);
            s.x += h.x; s.y += h.y; s.z += h.z; s.w += h.w;
            s2.x = fmaf(h.x, h.x, s2.x); s2.y = fmaf(h.y, h.y, s2.y);
            s2.z = fmaf(h.z, h.z, s2.z); s2.w = fmaf(h.w, h.w, s2.w);
        }
        *(float4*)&hmax[(long)pt*O + c4] = mx;
        *(float4*)&hmin[(long)pt*O + c4] = mn;
    }
    *(float4*)&ldsS [sub*O + c4] = s;
    *(float4*)&ldsS2[sub*O + c4] = s2;
    __syncthreads();
    if (tid < O) {
        float a = 0.f, b = 0.f;
        for (int u = 0; u < nsub; ++u) { a += ldsS[u*O + tid]; b += ldsS2[u*O + tid]; }
        partial[(long)wg*2*O + tid] = a;
        partial[(long)wg*2*O + O + tid] = b;
    }
}

// ---------------- column-sum of a chunk of rows ----------------
__global__ __launch_bounds__(256) void k_colsum(const float* __restrict__ partial,
                                                float* __restrict__ out, int W, int rpc) {
    int c = blockIdx.x*256 + threadIdx.x;
    if (c >= W) return;
    long r0 = (long)blockIdx.y * rpc;
    float s = 0.f;
    for (int r = 0; r < rpc; ++r) s += partial[(r0 + r)*W + c];
    out[(long)blockIdx.y*W + c] = s;
}

// ---------------- scale/shift from sums ----------------
__global__ __launch_bounds__(256) void k_bn_finalize(
    const float* __restrict__ sums, const float* __restrict__ g,
    const float* __restrict__ beta, float* __restrict__ ss, int O, float invCnt)
{
    int o = blockIdx.x*256 + threadIdx.x;
    if (o >= O) return;
    float mean = sums[o]*invCnt;
    float var  = sums[O + o]*invCnt - mean*mean;
    float sc = g[o] * rsqrtf(var + 1e-5f);
    ss[o] = sc;
    ss[O + o] = beta[o] - mean*sc;
}

// ---------------- apply BN + lrelu to hmax/hmin; also write fp16 into catH ----------------
__global__ __launch_bounds__(256) void k_edge_apply(
    const float* __restrict__ hmax, const float* __restrict__ hmin,
    const float* __restrict__ ss, float* __restrict__ out, int O,
    f16* __restrict__ catH, int co, int lg2O)
{
    long i4 = (long)blockIdx.x*256 + threadIdx.x;   // float4 index
    int c4 = (int)(i4 & ((O >> 2) - 1)) << 2;
    int pt = (int)(i4 >> (lg2O - 2));
    float4 mx = *(const float4*)&hmax[i4*4];
    float4 mn = *(const float4*)&hmin[i4*4];
    float4 y;
    {
        float sc = ss[c4+0], sh = ss[O+c4+0];
        float v = fmaf(sc >= 0.f ? mx.x : mn.x, sc, sh); y.x = LRELU(v);
    }
    {
        float sc = ss[c4+1], sh = ss[O+c4+1];
        float v = fmaf(sc >= 0.f ? mx.y : mn.y, sc, sh); y.y = LRELU(v);
    }
    {
        float sc = ss[c4+2], sh = ss[O+c4+2];
        float v = fmaf(sc >= 0.f ? mx.z : mn.z, sc, sh); y.z = LRELU(v);
    }
    {
        float sc = ss[c4+3], sh = ss[O+c4+3];
        float v = fmaf(sc >= 0.f ? mx.w : mn.w, sc, sh); y.w = LRELU(v);
    }
    *(float4*)&out[i4*4] = y;
    f16x4 hv;
    hv[0] = (f16)y.x; hv[1] = (f16)y.y; hv[2] = (f16)y.z; hv[3] = (f16)y.w;
    *(f16x4*)&catH[(long)pt*512 + co + c4] = hv;
}

// ---------------- h5 stats partials (deterministic) ----------------
__global__ __launch_bounds__(256) void k_h5_stats_p(const float* __restrict__ h5,
                                                    float* __restrict__ partial) {
    int tid = threadIdx.x, bid = blockIdx.x;   // 2048 blocks, 16 points each
    int base = bid*16;
    float s[4] = {0,0,0,0}, s2[4] = {0,0,0,0};
    for (int i = 0; i < 16; ++i) {
        long row = (long)(base + i)*1024;
        #pragma unroll
        for (int cc = 0; cc < 4; ++cc) {
            float v = h5[row + cc*256 + tid];
            s[cc] += v; s2[cc] = fmaf(v, v, s2[cc]);
        }
    }
    #pragma unroll
    for (int cc = 0; cc < 4; ++cc) {
        partial[(long)bid*2048 + cc*256 + tid] = s[cc];
        partial[(long)bid*2048 + 1024 + cc*256 + tid] = s2[cc];
    }
}

// ---------------- f-reduction stage A ----------------
__global__ __launch_bounds__(256) void k_reduce_fp(const float* __restrict__ h5,
                                                   const float* __restrict__ ss,
                                                   float* __restrict__ fpart) {
    int b = blockIdx.x, ch = blockIdx.y;
    int c = blockIdx.z*256 + threadIdx.x;
    float sc = ss[c], sh = ss[1024 + c];
    float mx = -INFINITY, sm = 0.f;
    int n0 = ch*128;
    for (int n = n0; n < n0 + 128; ++n) {
        float v = h5[((long)(b*2048 + n))*1024 + c];
        float y = fmaf(v, sc, sh); y = LRELU(y);
        mx = fmaxf(mx, y); sm += y;
    }
    fpart[((long)(b*16 + ch))*2048 + c] = mx;
    fpart[((long)(b*16 + ch))*2048 + 1024 + c] = sm;
}

// ---------------- f-reduction stage B ----------------
__global__ __launch_bounds__(256) void k_reduce_ff(const float* __restrict__ fpart,
                                                   float* __restrict__ f) {
    int b = blockIdx.x;
    int c = blockIdx.y*256 + threadIdx.x;
    float mx = -INFINITY, sm = 0.f;
    for (int ch = 0; ch < 16; ++ch) {
        mx = fmaxf(mx, fpart[((long)(b*16 + ch))*2048 + c]);
        sm += fpart[((long)(b*16 + ch))*2048 + 1024 + c];
    }
    f[(long)b*2048 + c] = mx;
    f[(long)b*2048 + 1024 + c] = sm * (1.f/2048.f);
}

// ---------------- small FC matmul ----------------
__global__ __launch_bounds__(256) void k_fc_mm(const float* __restrict__ X,
                                               const float* __restrict__ W,
                                               const float* __restrict__ bias,
                                               float* __restrict__ Y,
                                               int Kdim, int Ncol) {
    int t = blockIdx.x*256 + threadIdx.x;
    if (t >= 16*Ncol) return;
    int b = t / Ncol, j = t % Ncol;
    const float* xr = X + (long)b*Kdim;
    const float* wr = W + (long)j*Kdim;
    float s = 0.f;
    for (int k = 0; k < Kdim; k++) s = fmaf(xr[k], wr[k], s);
    Y[t] = s + (bias ? bias[j] : 0.f);
}

// ---------------- BN over batch axis (16) + lrelu ----------------
__global__ __launch_bounds__(256) void k_bn_rows(const float* __restrict__ X,
                                                 const float* __restrict__ g,
                                                 const float* __restrict__ be,
                                                 float* __restrict__ Y, int Ncol) {
    int j = blockIdx.x*256 + threadIdx.x;
    if (j >= Ncol) return;
    float s = 0.f, s2 = 0.f;
    for (int b = 0; b < 16; b++) { float v = X[b*Ncol + j]; s += v; s2 = fmaf(v, v, s2); }
    float mean = s*(1.f/16.f);
    float var  = s2*(1.f/16.f) - mean*mean;
    float sc = g[j]*rsqrtf(var + 1e-5f);
    float sh = be[j] - mean*sc;
    for (int b = 0; b < 16; b++) {
        float v = fmaf(X[b*Ncol + j], sc, sh);
        Y[b*Ncol + j] = LRELU(v);
    }
}

extern "C" void kernel_launch(void* const* d_in, const int* in_sizes, int n_in,
                              void* d_out, int out_size, void* d_ws, size_t ws_size,
                              hipStream_t stream) {
    const float* data = (const float*)d_in[0];
    const float* W1 = (const float*)d_in[1];  const float* g1 = (const float*)d_in[2];  const float* b1 = (const float*)d_in[3];
    const float* W2 = (const float*)d_in[4];  const float* g2 = (const float*)d_in[5];  const float* b2 = (const float*)d_in[6];
    const float* W3 = (const float*)d_in[7];  const float* g3 = (const float*)d_in[8];  const float* b3 = (const float*)d_in[9];
    const float* W4 = (const float*)d_in[10]; const float* g4 = (const float*)d_in[11]; const float* b4 = (const float*)d_in[12];
    const float* W5 = (const float*)d_in[13]; const float* g5 = (const float*)d_in[14]; const float* b5 = (const float*)d_in[15];
    const float* fc1W = (const float*)d_in[16]; const float* bn1g = (const float*)d_in[17]; const float* bn1b = (const float*)d_in[18];
    const float* fc2W = (const float*)d_in[19]; const float* fc2b = (const float*)d_in[20];
    const float* bn2g = (const float*)d_in[21]; const float* bn2b = (const float*)d_in[22];
    const float* fc3W = (const float*)d_in[23]; const float* fc3b = (const float*)d_in[24];

    void* wsym = nullptr;
    hipGetSymbolAddress(&wsym, HIP_SYMBOL(g_ws));
    char* w = (char*)wsym;
    size_t off = 0;
    auto alloc = [&](size_t bytes) { void* r = w + off; off += (bytes + 255) & ~size_t(255); return r; };
    float* S   = (float*)alloc(134217728);      // dist (8 batches) / h5 / hmax+hmin+partial
    float* x0  = (float*)alloc(393216);
    float* d1  = (float*)alloc(8388608);
    float* d2  = (float*)alloc(8388608);
    float* d3  = (float*)alloc(16777216);
    float* d4  = (float*)alloc(33554432);
    float* p   = (float*)alloc(33554432);
    float* q   = (float*)alloc(33554432);
    int*   idxb= (int*)  alloc(2621440);
    float* sqb = (float*)alloc(131072);
    float* Wd  = (float*)alloc(131072);
    float* sums= (float*)alloc(8192);
    float* ssb = (float*)alloc(8192);
    float* f   = (float*)alloc(131072);
    float* t1  = (float*)alloc(32768);
    float* a1  = (float*)alloc(32768);
    float* t2  = (float*)alloc(16384);
    float* a2  = (float*)alloc(16384);
    f16*  catH = (f16*) alloc(33554432);        // [32768][512] fp16 cat buffer
    f16*  W5H  = (f16*) alloc(1048576);         // [1024][512] fp16
    (void)ws_size; (void)n_in; (void)in_sizes; (void)out_size; (void)d_ws;

    // aliases inside S / dead buffers (live ranges don't overlap):
    float* hmaxb = S;                 // 32768*O <= 8.39M floats
    float* hminb = S + 8388608;
    float* partb = S + 16777216;      // 2048 x 2*O <= 1.05M floats
    float* part2 = S + 18874368;      // 32 x 2*O chunk sums
    float* h5par = d4;                // h5 stats partials (16 MB), d4 dead after cat-GEMM
    float* h5pt2 = d2;                // 32 x 2048 chunk sums, d2 dead after cat-GEMM
    float* fpart = d1;                // f-reduce partials (2 MB), d1 dead after cat-GEMM

    k_transpose_in<<<128, 256, 0, stream>>>(data, x0);

    auto layer = [&](const float* x, int C, int O, int lg2TPP, int lg2O, int co,
                     const float* W, const float* g, const float* beta, float* out) {
        k_sqnorm<<<128, 256, 0, stream>>>(x, sqb, C);
        for (int ch = 0; ch < 2; ch++) {
            const float* xc = x + (long)ch*16384*C;
            k_gemm_nt<<<dim3(16,16,8), 256, 0, stream>>>(
                xc, C, (long)2048*C, xc, C, (long)2048*C,
                S, 2048, (long)2048*2048, C, 2048, 2, sqb + ch*16384, 2048);
            k_topk20<<<4096, 256, 0, stream>>>(S, idxb, ch*16384);
        }
        k_wdiff<<<(O*C + 255)/256, 256, 0, stream>>>(W, Wd, O, C);
        k_gemm_nt<<<dim3(256, (O+127)/128, 1), 256, 0, stream>>>(
            x, C, 0, W, 2*C, 0, p, O, 0, C, O, 0, nullptr, 0);
        k_gemm_nt<<<dim3(256, (O+127)/128, 1), 256, 0, stream>>>(
            x, C, 0, Wd, C, 0, q, O, 0, C, O, 0, nullptr, 0);
        k_edge_gather<<<2048, 256, 0, stream>>>(p, q, idxb, hmaxb, hminb, partb, O, lg2TPP);
        // two-stage deterministic column sum: 2048 rows -> 32 -> 1
        k_colsum<<<dim3((2*O + 255)/256, 32), 256, 0, stream>>>(partb, part2, 2*O, 64);
        k_colsum<<<dim3((2*O + 255)/256, 1),  256, 0, stream>>>(part2, sums,  2*O, 32);
        k_bn_finalize<<<(O+255)/256, 256, 0, stream>>>(sums, g, beta, ssb, O, 1.f/655360.f);
        k_edge_apply<<<32*O, 256, 0, stream>>>(hmaxb, hminb, ssb, out, O, catH, co, lg2O);
    };

    layer(x0, 3,   64,  4, 6, 0,   W1, g1, b1, d1);
    layer(d1, 64,  64,  4, 6, 64,  W2, g2, b2, d2);
    layer(d2, 64,  128, 5, 7, 128, W3, g3, b3, d3);
    layer(d3, 128, 256, 6, 8, 256, W4, g4, b4, d4);

    // h5 = catH @ W5H^T via fp16 MFMA
    k_cvt_f16<<<2048, 256, 0, stream>>>(W5, W5H, 524288);
    k_gemm_mfma_nt<<<dim3(256, 8), 256, 0, stream>>>(catH, 512, W5H, 512, S, 1024, 512);

    // h5 BN stats (deterministic two-stage) + fused BN+lrelu+max/mean reduce
    k_h5_stats_p<<<2048, 256, 0, stream>>>(S, h5par);
    k_colsum<<<dim3(8, 32), 256, 0, stream>>>(h5par, h5pt2, 2048, 64);
    k_colsum<<<dim3(8, 1),  256, 0, stream>>>(h5pt2, sums,  2048, 32);
    k_bn_finalize<<<4, 256, 0, stream>>>(sums, g5, b5, ssb, 1024, 1.f/32768.f);
    k_reduce_fp<<<dim3(16,16,4), 256, 0, stream>>>(S, ssb, fpart);
    k_reduce_ff<<<dim3(16,4), 256, 0, stream>>>(fpart, f);

    k_fc_mm<<<32, 256, 0, stream>>>(f,  fc1W, nullptr, t1, 2048, 512);
    k_bn_rows<<<2, 256, 0, stream>>>(t1, bn1g, bn1b, a1, 512);
    k_fc_mm<<<16, 256, 0, stream>>>(a1, fc2W, fc2b, t2, 512, 256);
    k_bn_rows<<<1, 256, 0, stream>>>(t2, bn2g, bn2b, a2, 256);
    k_fc_mm<<<3, 256, 0, stream>>>(a2, fc3W, fc3b, (float*)d_out, 256, 40);
}

// Round 8
// 2017.945 us; speedup vs baseline: 2.4802x; 1.1885x over previous
//
#include <hip/hip_runtime.h>
#include <math.h>

#define LRELU(x) ((x) >= 0.f ? (x) : 0.2f*(x))

typedef _Float16 f16;
typedef f16 f16x8 __attribute__((ext_vector_type(8)));
typedef f16 f16x4 __attribute__((ext_vector_type(4)));
typedef float f32x4 __attribute__((ext_vector_type(4)));

// ---- static device scratch (312 MB): independent of harness ws_size ----
#define WS_FLOATS 78000000u
__device__ __align__(256) float g_ws[WS_FLOATS];

// ---------------- transpose (B,3,N) -> (B*N,3) ----------------
__global__ __launch_bounds__(256) void k_transpose_in(const float* __restrict__ data,
                                                      float* __restrict__ x0) {
    int i = blockIdx.x*256 + threadIdx.x;      // over B*N = 32768
    int b = i >> 11, n = i & 2047;
    #pragma unroll
    for (int c = 0; c < 3; c++)
        x0[(long)i*3 + c] = data[((long)b*3 + c)*2048 + n];
}

// ---------------- squared norms ----------------
__global__ __launch_bounds__(256) void k_sqnorm(const float* __restrict__ x,
                                                float* __restrict__ sq, int C) {
    int i = blockIdx.x*256 + threadIdx.x;      // over 32768 points
    const float* xr = x + (long)i*C;
    float s = 0.f;
    for (int c = 0; c < C; c++) s = fmaf(xr[c], xr[c], s);
    sq[i] = s;
}

// ---------------- fp32 GEMM: C[i,j] = sum_k A[i,k]*B[j,k] ----------------
// mode 0: store; mode 2: dist epilogue 2*acc - sq[i] - sq[j]
#define KC 8
__global__ __launch_bounds__(256) void k_gemm_nt(
    const float* __restrict__ A, int lda, long sAb,
    const float* __restrict__ B, int ldb, long sBb,
    float* __restrict__ Cm, int ldc, long sCb,
    int K, int Nj, int mode, const float* __restrict__ sq, int sqStride)
{
    __shared__ float As[KC][132];
    __shared__ float Bs[KC][132];
    int z = blockIdx.z;
    const float* Ab = A + (long)z*sAb;
    const float* Bb = B + (long)z*sBb;
    float* Cb = Cm + (long)z*sCb;
    int rowBase = blockIdx.x*128, colBase = blockIdx.y*128;
    int tid = threadIdx.x, tx = tid & 15, ty = tid >> 4;
    float acc[8][8] = {};
    for (int k0 = 0; k0 < K; k0 += KC) {
        #pragma unroll
        for (int l = 0; l < 4; l++) {
            int id = tid + l*256;
            int kk = id & 7, r = id >> 3;   // r in 0..127
            float av = 0.f, bv = 0.f;
            if (k0 + kk < K) {
                av = Ab[(long)(rowBase + r)*lda + k0 + kk];
                if (colBase + r < Nj)
                    bv = Bb[(long)(colBase + r)*ldb + k0 + kk];
            }
            As[kk][r] = av; Bs[kk][r] = bv;
        }
        __syncthreads();
        #pragma unroll
        for (int kk = 0; kk < KC; kk++) {
            float4 a0 = *(const float4*)&As[kk][ty*8];
            float4 a1 = *(const float4*)&As[kk][ty*8 + 4];
            float4 b0 = *(const float4*)&Bs[kk][tx*4];
            float4 b1 = *(const float4*)&Bs[kk][64 + tx*4];
            float a[8] = {a0.x,a0.y,a0.z,a0.w,a1.x,a1.y,a1.z,a1.w};
            float b[8] = {b0.x,b0.y,b0.z,b0.w,b1.x,b1.y,b1.z,b1.w};
            #pragma unroll
            for (int i = 0; i < 8; i++)
                #pragma unroll
                for (int j = 0; j < 8; j++)
                    acc[i][j] = fmaf(a[i], b[j], acc[i][j]);
        }
        __syncthreads();
    }
    const float* sqz = sq + (long)z*sqStride;  // only dereferenced in mode 2
    #pragma unroll
    for (int i = 0; i < 8; i++) {
        int r = rowBase + ty*8 + i;
        float sqr = (mode == 2) ? sqz[r] : 0.f;
        #pragma unroll
        for (int half = 0; half < 2; half++) {
            int c = colBase + half*64 + tx*4;
            int jb = half*4;
            if (c + 3 < Nj) {
                float4 v;
                v.x = acc[i][jb+0]; v.y = acc[i][jb+1];
                v.z = acc[i][jb+2]; v.w = acc[i][jb+3];
                if (mode == 2) {
                    v.x = 2.f*v.x - sqr - sqz[c+0];
                    v.y = 2.f*v.y - sqr - sqz[c+1];
                    v.z = 2.f*v.z - sqr - sqz[c+2];
                    v.w = 2.f*v.w - sqr - sqz[c+3];
                }
                *(float4*)&Cb[(long)r*ldc + c] = v;
            } else {
                #pragma unroll
                for (int j = 0; j < 4; j++) {
                    int c2 = c + j;
                    if (c2 >= Nj) continue;
                    float v = acc[i][jb+j];
                    if (mode == 2) v = 2.f*v - sqr - sqz[c2];
                    Cb[(long)r*ldc + c2] = v;
                }
            }
        }
    }
}

// ---------------- fp16 MFMA GEMM: C[m][n] = sum_k A[m][k]*B[n][k] ----------------
__global__ __launch_bounds__(256) void k_gemm_mfma_nt(
    const f16* __restrict__ A, int lda,
    const f16* __restrict__ Bm, int ldb,
    float* __restrict__ Cm, int ldc, int K)
{
    __shared__ f16 As[128][40];   // pad to 40 halves (80 B) -> 2-way bank aliasing (free)
    __shared__ f16 Bs[128][40];
    int t = threadIdx.x;
    int rowBase = blockIdx.x*128, colBase = blockIdx.y*128;
    int wave = t >> 6, l = t & 63;
    int wrow = (wave >> 1)*64, wcol = (wave & 1)*64;
    int lr = l & 15, kg = l >> 4;
    int sr = t >> 1, seg = (t & 1)*16;   // staging: row 0..127, 16-half segment

    f32x4 acc[4][4] = {};
    for (int k0 = 0; k0 < K; k0 += 32) {
        const f16* ga = A  + (long)(rowBase + sr)*lda + k0 + seg;
        const f16* gb = Bm + (long)(colBase + sr)*ldb + k0 + seg;
        uint4 a0 = *(const uint4*)ga;
        uint4 a1 = *(const uint4*)(ga + 8);
        uint4 b0 = *(const uint4*)gb;
        uint4 b1 = *(const uint4*)(gb + 8);
        *(uint4*)&As[sr][seg]     = a0;
        *(uint4*)&As[sr][seg + 8] = a1;
        *(uint4*)&Bs[sr][seg]     = b0;
        *(uint4*)&Bs[sr][seg + 8] = b1;
        __syncthreads();
        f16x8 af[4], bf[4];
        #pragma unroll
        for (int i = 0; i < 4; i++) af[i] = *(const f16x8*)&As[wrow + i*16 + lr][kg*8];
        #pragma unroll
        for (int j = 0; j < 4; j++) bf[j] = *(const f16x8*)&Bs[wcol + j*16 + lr][kg*8];
        #pragma unroll
        for (int i = 0; i < 4; i++)
            #pragma unroll
            for (int j = 0; j < 4; j++)
                acc[i][j] = __builtin_amdgcn_mfma_f32_16x16x32_f16(af[i], bf[j], acc[i][j], 0, 0, 0);
        __syncthreads();
    }
    // D mapping (m89, dtype-independent): col = lane&15, row = (lane>>4)*4 + reg
    #pragma unroll
    for (int i = 0; i < 4; i++) {
        #pragma unroll
        for (int j = 0; j < 4; j++) {
            int row = rowBase + wrow + i*16 + kg*4;
            int col = colBase + wcol + j*16 + lr;
            #pragma unroll
            for (int r2 = 0; r2 < 4; r2++)
                Cm[(long)(row + r2)*ldc + col] = acc[i][j][r2];
        }
    }
}

// ---------------- fp32 -> fp16 elementwise ----------------
__global__ __launch_bounds__(256) void k_cvt_f16(const float* __restrict__ in,
                                                 f16* __restrict__ out, int n) {
    int i = blockIdx.x*256 + threadIdx.x;
    if (i < n) out[i] = (f16)in[i];
}

// ---------------- top-20 per row (value desc, index asc ties) ----------------
__global__ __launch_bounds__(256) void k_topk20(const float* __restrict__ dist,
                                                int* __restrict__ idxOut, int rowOffset)
{
    __shared__ float lds[4][2048];
    int wave = threadIdx.x >> 6, lane = threadIdx.x & 63;
    int row = blockIdx.x*4 + wave;
    const float* dr = dist + (long)row*2048;
    float* L = lds[wave];
    for (int i = 0; i < 32; i++) L[i*64 + lane] = dr[i*64 + lane];
    __syncthreads();
    int* out = idxOut + (long)(rowOffset + row)*20;
    for (int it = 0; it < 20; it++) {
        float bv = -INFINITY; int bi = 0x7fffffff;
        for (int i = 0; i < 32; i++) {
            float v = L[i*64 + lane];
            if (v > bv) { bv = v; bi = i*64 + lane; }
        }
        #pragma unroll
        for (int s = 32; s > 0; s >>= 1) {
            float ov = __shfl_xor(bv, s);
            int   oi = __shfl_xor(bi, s);
            if (ov > bv || (ov == bv && oi < bi)) { bv = ov; bi = oi; }
        }
        if (lane == 0) out[it] = bi;
        if (lane == (bi & 63)) L[bi] = -INFINITY;
    }
}

// ---------------- Wd = W[:,C:] - W[:,:C] ----------------
__global__ __launch_bounds__(256) void k_wdiff(const float* __restrict__ W,
                                               float* __restrict__ Wd, int O, int C) {
    int i = blockIdx.x*256 + threadIdx.x;
    if (i >= O*C) return;
    int o = i / C, c = i % C;
    Wd[o*C + c] = W[(long)o*2*C + C + c] - W[(long)o*2*C + c];
}

// ---------------- fused gather: hmax/hmin per (pt,c) + block stats partials ----------------
__global__ __launch_bounds__(256) void k_edge_gather(
    const float* __restrict__ p, const float* __restrict__ q,
    const int* __restrict__ idx,
    float* __restrict__ hmax, float* __restrict__ hmin,
    float* __restrict__ partial, int O, int lg2TPP)
{
    __shared__ float ldsS[1024];
    __shared__ float ldsS2[1024];
    int tid = threadIdx.x;
    int TPP = O >> 2;                    // threads per point
    int c4 = (tid & (TPP - 1)) << 2;
    int sub = tid >> lg2TPP;
    int nsub = 256 >> lg2TPP;            // points in flight
    int wg = blockIdx.x;
    int logical = (wg & 7)*256 + (wg >> 3);   // XCD swizzle: 2 batches per XCD
    int base = logical*16;
    float4 s = {0,0,0,0}, s2 = {0,0,0,0};
    int iters = 16 / nsub;
    for (int it = 0; it < iters; ++it) {
        int pt = base + sub + it*nsub;
        int bb = (pt >> 11) << 11;
        const int* ir = idx + (long)pt*20;
        float4 qv = *(const float4*)&q[(long)pt*O + c4];
        float4 mx = {-INFINITY,-INFINITY,-INFINITY,-INFINITY};
        float4 mn = { INFINITY, INFINITY, INFINITY, INFINITY};
        for (int k = 0; k < 20; ++k) {
            int m = ir[k];
            float4 pv = *(const float4*)&p[(long)(bb + m)*O + c4];
            float4 h;
            h.x = pv.x + qv.x; h.y = pv.y + qv.y;
            h.z = pv.z + qv.z; h.w = pv.w + qv.w;
            mx.x = fmaxf(mx.x, h.x); mx.y = fmaxf(mx.y, h.y);
            mx.z = fmaxf(mx.z, h.z); mx.w = fmaxf(mx.w, h.w);
            mn.x = fminf(mn.x, h.x); mn.y = fminf(mn.y, h.y);
            mn.z = fminf(mn.z, h.z); mn.w = fminf(mn.w, h.w);
            s.x += h.x; s.y += h.y; s.z += h.z; s.w += h.w;
            s2.x = fmaf(h.x, h.x, s2.x); s2.y = fmaf(h.y, h.y, s2.y);
            s2.z = fmaf(h.z, h.z, s2.z); s2.w = fmaf(h.w, h.w, s2.w);
        }
        *(float4*)&hmax[(long)pt*O + c4] = mx;
        *(float4*)&hmin[(long)pt*O + c4] = mn;
    }
    *(float4*)&ldsS [sub*O + c4] = s;
    *(float4*)&ldsS2[sub*O + c4] = s2;
    __syncthreads();
    if (tid < O) {
        float a = 0.f, b = 0.f;
        for (int u = 0; u < nsub; ++u) { a += ldsS[u*O + tid]; b += ldsS2[u*O + tid]; }
        partial[(long)wg*2*O + tid] = a;
        partial[(long)wg*2*O + O + tid] = b;
    }
}

// ---------------- column-sum of a chunk of rows ----------------
__global__ __launch_bounds__(256) void k_colsum(const float* __restrict__ partial,
                                                float* __restrict__ out, int W, int rpc) {
    int c = blockIdx.x*256 + threadIdx.x;
    if (c >= W) return;
    long r0 = (long)blockIdx.y * rpc;
    float s = 0.f;
    for (int r = 0; r < rpc; ++r) s += partial[(r0 + r)*W + c];
    out[(long)blockIdx.y*W + c] = s;
}

// ---------------- scale/shift from sums ----------------
__global__ __launch_bounds__(256) void k_bn_finalize(
    const float* __restrict__ sums, const float* __restrict__ g,
    const float* __restrict__ beta, float* __restrict__ ss, int O, float invCnt)
{
    int o = blockIdx.x*256 + threadIdx.x;
    if (o >= O) return;
    float mean = sums[o]*invCnt;
    float var  = sums[O + o]*invCnt - mean*mean;
    float sc = g[o] * rsqrtf(var + 1e-5f);
    ss[o] = sc;
    ss[O + o] = beta[o] - mean*sc;
}

// ---------------- apply BN + lrelu to hmax/hmin; also write fp16 into catH ----------------
__global__ __launch_bounds__(256) void k_edge_apply(
    const float* __restrict__ hmax, const float* __restrict__ hmin,
    const float* __restrict__ ss, float* __restrict__ out, int O,
    f16* __restrict__ catH, int co, int lg2O)
{
    long i4 = (long)blockIdx.x*256 + threadIdx.x;   // float4 index
    int c4 = (int)(i4 & ((O >> 2) - 1)) << 2;
    int pt = (int)(i4 >> (lg2O - 2));
    float4 mx = *(const float4*)&hmax[i4*4];
    float4 mn = *(const float4*)&hmin[i4*4];
    float4 y;
    {
        float sc = ss[c4+0], sh = ss[O+c4+0];
        float v = fmaf(sc >= 0.f ? mx.x : mn.x, sc, sh); y.x = LRELU(v);
    }
    {
        float sc = ss[c4+1], sh = ss[O+c4+1];
        float v = fmaf(sc >= 0.f ? mx.y : mn.y, sc, sh); y.y = LRELU(v);
    }
    {
        float sc = ss[c4+2], sh = ss[O+c4+2];
        float v = fmaf(sc >= 0.f ? mx.z : mn.z, sc, sh); y.z = LRELU(v);
    }
    {
        float sc = ss[c4+3], sh = ss[O+c4+3];
        float v = fmaf(sc >= 0.f ? mx.w : mn.w, sc, sh); y.w = LRELU(v);
    }
    *(float4*)&out[i4*4] = y;
    f16x4 hv;
    hv[0] = (f16)y.x; hv[1] = (f16)y.y; hv[2] = (f16)y.z; hv[3] = (f16)y.w;
    *(f16x4*)&catH[(long)pt*512 + co + c4] = hv;
}

// ---------------- h5 stats partials (deterministic) ----------------
__global__ __launch_bounds__(256) void k_h5_stats_p(const float* __restrict__ h5,
                                                    float* __restrict__ partial) {
    int tid = threadIdx.x, bid = blockIdx.x;   // 2048 blocks, 16 points each
    int base = bid*16;
    float s[4] = {0,0,0,0}, s2[4] = {0,0,0,0};
    for (int i = 0; i < 16; ++i) {
        long row = (long)(base + i)*1024;
        #pragma unroll
        for (int cc = 0; cc < 4; ++cc) {
            float v = h5[row + cc*256 + tid];
            s[cc] += v; s2[cc] = fmaf(v, v, s2[cc]);
        }
    }
    #pragma unroll
    for (int cc = 0; cc < 4; ++cc) {
        partial[(long)bid*2048 + cc*256 + tid] = s[cc];
        partial[(long)bid*2048 + 1024 + cc*256 + tid] = s2[cc];
    }
}

// ---------------- f-reduction stage A ----------------
__global__ __launch_bounds__(256) void k_reduce_fp(const float* __restrict__ h5,
                                                   const float* __restrict__ ss,
                                                   float* __restrict__ fpart) {
    int b = blockIdx.x, ch = blockIdx.y;
    int c = blockIdx.z*256 + threadIdx.x;
    float sc = ss[c], sh = ss[1024 + c];
    float mx = -INFINITY, sm = 0.f;
    int n0 = ch*128;
    for (int n = n0; n < n0 + 128; ++n) {
        float v = h5[((long)(b*2048 + n))*1024 + c];
        float y = fmaf(v, sc, sh); y = LRELU(y);
        mx = fmaxf(mx, y); sm += y;
    }
    fpart[((long)(b*16 + ch))*2048 + c] = mx;
    fpart[((long)(b*16 + ch))*2048 + 1024 + c] = sm;
}

// ---------------- f-reduction stage B ----------------
__global__ __launch_bounds__(256) void k_reduce_ff(const float* __restrict__ fpart,
                                                   float* __restrict__ f) {
    int b = blockIdx.x;
    int c = blockIdx.y*256 + threadIdx.x;
    float mx = -INFINITY, sm = 0.f;
    for (int ch = 0; ch < 16; ++ch) {
        mx = fmaxf(mx, fpart[((long)(b*16 + ch))*2048 + c]);
        sm += fpart[((long)(b*16 + ch))*2048 + 1024 + c];
    }
    f[(long)b*2048 + c] = mx;
    f[(long)b*2048 + 1024 + c] = sm * (1.f/2048.f);
}

// ---------------- FC matmul: wave-per-output, shuffle reduction ----------------
__global__ __launch_bounds__(256) void k_fc_wave(const float* __restrict__ X,
                                                 const float* __restrict__ W,
                                                 const float* __restrict__ bias,
                                                 float* __restrict__ Y,
                                                 int Kdim, int Ncol) {
    int wid = blockIdx.x*4 + (threadIdx.x >> 6);
    int lane = threadIdx.x & 63;
    if (wid >= 16*Ncol) return;
    int b = wid / Ncol, j = wid % Ncol;
    const float* xr = X + (long)b*Kdim;
    const float* wr = W + (long)j*Kdim;
    float s = 0.f;
    for (int k = lane*4; k < Kdim; k += 256) {
        float4 xv = *(const float4*)&xr[k];
        float4 wv = *(const float4*)&wr[k];
        s = fmaf(xv.x, wv.x, s); s = fmaf(xv.y, wv.y, s);
        s = fmaf(xv.z, wv.z, s); s = fmaf(xv.w, wv.w, s);
    }
    #pragma unroll
    for (int sft = 32; sft > 0; sft >>= 1) s += __shfl_xor(s, sft);
    if (lane == 0) Y[wid] = s + (bias ? bias[j] : 0.f);
}

// ---------------- BN over batch axis (16) + lrelu ----------------
__global__ __launch_bounds__(256) void k_bn_rows(const float* __restrict__ X,
                                                 const float* __restrict__ g,
                                                 const float* __restrict__ be,
                                                 float* __restrict__ Y, int Ncol) {
    int j = blockIdx.x*256 + threadIdx.x;
    if (j >= Ncol) return;
    float s = 0.f, s2 = 0.f;
    for (int b = 0; b < 16; b++) { float v = X[b*Ncol + j]; s += v; s2 = fmaf(v, v, s2); }
    float mean = s*(1.f/16.f);
    float var  = s2*(1.f/16.f) - mean*mean;
    float sc = g[j]*rsqrtf(var + 1e-5f);
    float sh = be[j] - mean*sc;
    for (int b = 0; b < 16; b++) {
        float v = fmaf(X[b*Ncol + j], sc, sh);
        Y[b*Ncol + j] = LRELU(v);
    }
}

extern "C" void kernel_launch(void* const* d_in, const int* in_sizes, int n_in,
                              void* d_out, int out_size, void* d_ws, size_t ws_size,
                              hipStream_t stream) {
    const float* data = (const float*)d_in[0];
    const float* W1 = (const float*)d_in[1];  const float* g1 = (const float*)d_in[2];  const float* b1 = (const float*)d_in[3];
    const float* W2 = (const float*)d_in[4];  const float* g2 = (const float*)d_in[5];  const float* b2 = (const float*)d_in[6];
    const float* W3 = (const float*)d_in[7];  const float* g3 = (const float*)d_in[8];  const float* b3 = (const float*)d_in[9];
    const float* W4 = (const float*)d_in[10]; const float* g4 = (const float*)d_in[11]; const float* b4 = (const float*)d_in[12];
    const float* W5 = (const float*)d_in[13]; const float* g5 = (const float*)d_in[14]; const float* b5 = (const float*)d_in[15];
    const float* fc1W = (const float*)d_in[16]; const float* bn1g = (const float*)d_in[17]; const float* bn1b = (const float*)d_in[18];
    const float* fc2W = (const float*)d_in[19]; const float* fc2b = (const float*)d_in[20];
    const float* bn2g = (const float*)d_in[21]; const float* bn2b = (const float*)d_in[22];
    const float* fc3W = (const float*)d_in[23]; const float* fc3b = (const float*)d_in[24];

    void* wsym = nullptr;
    hipGetSymbolAddress(&wsym, HIP_SYMBOL(g_ws));
    char* w = (char*)wsym;
    size_t off = 0;
    auto alloc = [&](size_t bytes) { void* r = w + off; off += (bytes + 255) & ~size_t(255); return r; };
    float* S   = (float*)alloc(134217728);      // dist (8 batches) / h5 / hmax+hmin+partial
    float* x0  = (float*)alloc(393216);
    float* d1  = (float*)alloc(8388608);
    float* d2  = (float*)alloc(8388608);
    float* d3  = (float*)alloc(16777216);
    float* d4  = (float*)alloc(33554432);
    float* p   = (float*)alloc(33554432);
    float* q   = (float*)alloc(33554432);
    int*   idxb= (int*)  alloc(2621440);
    float* sqb = (float*)alloc(131072);
    float* Wd  = (float*)alloc(131072);
    float* sums= (float*)alloc(8192);
    float* ssb = (float*)alloc(8192);
    float* f   = (float*)alloc(131072);
    float* t1  = (float*)alloc(32768);
    float* a1  = (float*)alloc(32768);
    float* t2  = (float*)alloc(16384);
    float* a2  = (float*)alloc(16384);
    f16*  catH = (f16*) alloc(33554432);        // [32768][512] fp16 cat buffer
    f16*  W5H  = (f16*) alloc(1048576);         // [1024][512] fp16
    (void)ws_size; (void)n_in; (void)in_sizes; (void)out_size; (void)d_ws;

    // aliases inside S / dead buffers (live ranges don't overlap):
    float* hmaxb = S;                 // 32768*O <= 8.39M floats
    float* hminb = S + 8388608;
    float* partb = S + 16777216;      // 2048 x 2*O <= 1.05M floats
    float* part2 = S + 18874368;      // 32 x 2*O chunk sums
    float* h5par = d4;                // h5 stats partials (16 MB), d4 dead after cat-GEMM
    float* h5pt2 = d2;                // 32 x 2048 chunk sums, d2 dead after cat-GEMM
    float* fpart = d1;                // f-reduce partials (2 MB), d1 dead after cat-GEMM

    k_transpose_in<<<128, 256, 0, stream>>>(data, x0);

    auto layer = [&](const float* x, int C, int O, int lg2TPP, int lg2O, int co,
                     const float* W, const float* g, const float* beta, float* out) {
        k_sqnorm<<<128, 256, 0, stream>>>(x, sqb, C);
        for (int ch = 0; ch < 2; ch++) {
            const float* xc = x + (long)ch*16384*C;
            k_gemm_nt<<<dim3(16,16,8), 256, 0, stream>>>(
                xc, C, (long)2048*C, xc, C, (long)2048*C,
                S, 2048, (long)2048*2048, C, 2048, 2, sqb + ch*16384, 2048);
            k_topk20<<<4096, 256, 0, stream>>>(S, idxb, ch*16384);
        }
        k_wdiff<<<(O*C + 255)/256, 256, 0, stream>>>(W, Wd, O, C);
        k_gemm_nt<<<dim3(256, (O+127)/128, 1), 256, 0, stream>>>(
            x, C, 0, W, 2*C, 0, p, O, 0, C, O, 0, nullptr, 0);
        k_gemm_nt<<<dim3(256, (O+127)/128, 1), 256, 0, stream>>>(
            x, C, 0, Wd, C, 0, q, O, 0, C, O, 0, nullptr, 0);
        k_edge_gather<<<2048, 256, 0, stream>>>(p, q, idxb, hmaxb, hminb, partb, O, lg2TPP);
        // two-stage deterministic column sum: 2048 rows -> 32 -> 1
        k_colsum<<<dim3((2*O + 255)/256, 32), 256, 0, stream>>>(partb, part2, 2*O, 64);
        k_colsum<<<dim3((2*O + 255)/256, 1),  256, 0, stream>>>(part2, sums,  2*O, 32);
        k_bn_finalize<<<(O+255)/256, 256, 0, stream>>>(sums, g, beta, ssb, O, 1.f/655360.f);
        k_edge_apply<<<32*O, 256, 0, stream>>>(hmaxb, hminb, ssb, out, O, catH, co, lg2O);
    };

    layer(x0, 3,   64,  4, 6, 0,   W1, g1, b1, d1);
    layer(d1, 64,  64,  4, 6, 64,  W2, g2, b2, d2);
    layer(d2, 64,  128, 5, 7, 128, W3, g3, b3, d3);
    layer(d3, 128, 256, 6, 8, 256, W4, g4, b4, d4);

    // h5 = catH @ W5H^T via fp16 MFMA
    k_cvt_f16<<<2048, 256, 0, stream>>>(W5, W5H, 524288);
    k_gemm_mfma_nt<<<dim3(256, 8), 256, 0, stream>>>(catH, 512, W5H, 512, S, 1024, 512);

    // h5 BN stats (deterministic two-stage) + fused BN+lrelu+max/mean reduce
    k_h5_stats_p<<<2048, 256, 0, stream>>>(S, h5par);
    k_colsum<<<dim3(8, 32), 256, 0, stream>>>(h5par, h5pt2, 2048, 64);
    k_colsum<<<dim3(8, 1),  256, 0, stream>>>(h5pt2, sums,  2048, 32);
    k_bn_finalize<<<4, 256, 0, stream>>>(sums, g5, b5, ssb, 1024, 1.f/32768.f);
    k_reduce_fp<<<dim3(16,16,4), 256, 0, stream>>>(S, ssb, fpart);
    k_reduce_ff<<<dim3(16,4), 256, 0, stream>>>(fpart, f);

    // FC head: wave-per-output reductions
    k_fc_wave<<<2048, 256, 0, stream>>>(f,  fc1W, nullptr, t1, 2048, 512);
    k_bn_rows<<<2, 256, 0, stream>>>(t1, bn1g, bn1b, a1, 512);
    k_fc_wave<<<1024, 256, 0, stream>>>(a1, fc2W, fc2b, t2, 512, 256);
    k_bn_rows<<<1, 256, 0, stream>>>(t2, bn2g, bn2b, a2, 256);
    k_fc_wave<<<160, 256, 0, stream>>>(a2, fc3W, fc3b, (float*)d_out, 256, 40);
}